// Round 1
// baseline (580.049 us; speedup 1.0000x reference)
//
#include <hip/hip_runtime.h>

typedef unsigned short u16;
typedef float f32x4 __attribute__((ext_vector_type(4)));
typedef __bf16 bf16x8 __attribute__((ext_vector_type(8)));
typedef unsigned int u32x4 __attribute__((ext_vector_type(4)));
typedef u16 u16x4 __attribute__((ext_vector_type(4)));

#define S_ 2048
#define D_ 1024
#define H_ 16
#define HD_ 64

__device__ __forceinline__ u16 f2bf(float f) {
  unsigned int u = __builtin_bit_cast(unsigned int, f);
  u += 0x7fffu + ((u >> 16) & 1u);
  return (u16)(u >> 16);
}

__device__ __forceinline__ f32x4 mfma16(bf16x8 a, bf16x8 b, f32x4 c) {
  return __builtin_amdgcn_mfma_f32_16x16x32_bf16(a, b, c, 0, 0, 0);
}

// ---------- cast fp32 -> bf16 (vectorized) ----------
__global__ void cast_kernel(const float* __restrict__ src, u16* __restrict__ dst, int n4) {
  int i = blockIdx.x * 256 + threadIdx.x;
  if (i >= n4) return;
  f32x4 v = *(const f32x4*)(src + (size_t)i * 4);
  u16x4 o;
  o[0] = f2bf(v[0]); o[1] = f2bf(v[1]); o[2] = f2bf(v[2]); o[3] = f2bf(v[3]);
  *(u16x4*)(dst + (size_t)i * 4) = o;
}

// ---------- cast + transpose fp32 W[R][C] -> bf16 WT[C][R] ----------
__global__ __launch_bounds__(256) void castT_kernel(const float* __restrict__ W,
                                                    u16* __restrict__ WT, int R, int Cn) {
  __shared__ float tile[32][33];
  int tx = threadIdx.x & 31, ty = threadIdx.x >> 5;
  int bc = blockIdx.x, br = blockIdx.y;
#pragma unroll
  for (int i = 0; i < 4; ++i)
    tile[ty + i * 8][tx] = W[(size_t)(br * 32 + ty + i * 8) * Cn + bc * 32 + tx];
  __syncthreads();
#pragma unroll
  for (int i = 0; i < 4; ++i)
    WT[(size_t)(bc * 32 + ty + i * 8) * R + br * 32 + tx] = f2bf(tile[tx][ty + i * 8]);
}

// ---------- bf16 transpose v[R][C] -> vT[C][R] ----------
__global__ __launch_bounds__(256) void transpose_bf16(const u16* __restrict__ V,
                                                      u16* __restrict__ VT, int R, int Cn) {
  __shared__ u16 tile[32][33];
  int tx = threadIdx.x & 31, ty = threadIdx.x >> 5;
  int bc = blockIdx.x, br = blockIdx.y;
#pragma unroll
  for (int i = 0; i < 4; ++i)
    tile[ty + i * 8][tx] = V[(size_t)(br * 32 + ty + i * 8) * Cn + bc * 32 + tx];
  __syncthreads();
#pragma unroll
  for (int i = 0; i < 4; ++i)
    VT[(size_t)(bc * 32 + ty + i * 8) * R + br * 32 + tx] = tile[tx][ty + i * 8];
}

// ---------- GEMM: C[M=2048][N=1024] = A[2048][K] * BT[n][k]  (bf16, MFMA) ----------
// A optionally concatenated from A0|A1 along K at ksplit. 128x128 tile, BK=32, 4 waves.
template <int CF32>
__global__ __launch_bounds__(256) void gemm_kernel(const u16* __restrict__ A0,
                                                   const u16* __restrict__ A1, int ksplit,
                                                   const u16* __restrict__ BT,
                                                   void* __restrict__ Cp, int K) {
  __shared__ u16 As[128 * 32];
  __shared__ u16 Bs[128 * 32];
  const int tid = threadIdx.x, l = tid & 63, w = tid >> 6;
  const int wm = w >> 1, wn = w & 1;
  const int bm = blockIdx.y, bn = blockIdx.x;
  f32x4 zf = {0.f, 0.f, 0.f, 0.f};
  f32x4 acc[4][4];
#pragma unroll
  for (int mi = 0; mi < 4; ++mi)
#pragma unroll
    for (int ni = 0; ni < 4; ++ni) acc[mi][ni] = zf;

  for (int k0 = 0; k0 < K; k0 += 32) {
    __syncthreads();
#pragma unroll
    for (int i = 0; i < 2; ++i) {  // stage A: 128 rows x 4 chunks(16B)
      int idx = tid + i * 256, r = idx >> 2, c = idx & 3;
      int k = k0 + c * 8;
      const u16* src = (k < ksplit) ? (A0 + (size_t)(bm * 128 + r) * D_ + k)
                                    : (A1 + (size_t)(bm * 128 + r) * D_ + (k - ksplit));
      u32x4 v = *(const u32x4*)src;
      *(u32x4*)(As + r * 32 + (c ^ ((r >> 1) & 3)) * 8) = v;
    }
#pragma unroll
    for (int i = 0; i < 2; ++i) {  // stage BT rows (n-major)
      int idx = tid + i * 256, r = idx >> 2, c = idx & 3;
      int k = k0 + c * 8;
      u32x4 v = *(const u32x4*)(BT + (size_t)(bn * 128 + r) * K + k);
      *(u32x4*)(Bs + r * 32 + (c ^ ((r >> 1) & 3)) * 8) = v;
    }
    __syncthreads();
    bf16x8 af[4], bfr[4];
#pragma unroll
    for (int mi = 0; mi < 4; ++mi) {
      int row = wm * 64 + mi * 16 + (l & 15);
      int slot = (l >> 4) ^ ((row >> 1) & 3);
      af[mi] = __builtin_bit_cast(bf16x8, *(const u32x4*)(As + row * 32 + slot * 8));
    }
#pragma unroll
    for (int ni = 0; ni < 4; ++ni) {
      int row = wn * 64 + ni * 16 + (l & 15);
      int slot = (l >> 4) ^ ((row >> 1) & 3);
      bfr[ni] = __builtin_bit_cast(bf16x8, *(const u32x4*)(Bs + row * 32 + slot * 8));
    }
#pragma unroll
    for (int mi = 0; mi < 4; ++mi)
#pragma unroll
      for (int ni = 0; ni < 4; ++ni) acc[mi][ni] = mfma16(af[mi], bfr[ni], acc[mi][ni]);
  }
#pragma unroll
  for (int mi = 0; mi < 4; ++mi)
#pragma unroll
    for (int ni = 0; ni < 4; ++ni)
#pragma unroll
      for (int r = 0; r < 4; ++r) {
        int row = bm * 128 + wm * 64 + mi * 16 + (l >> 4) * 4 + r;
        int col = bn * 128 + wn * 64 + ni * 16 + (l & 15);
        if (CF32)
          ((float*)Cp)[(size_t)row * D_ + col] = acc[mi][ni][r];
        else
          ((u16*)Cp)[(size_t)row * D_ + col] = f2bf(acc[mi][ni][r]);
      }
}

// ---------- 64x64 bf16 tile stage with XOR swizzle (8 chunks of 16B per 128B row) ----------
__device__ __forceinline__ void stage64(u16* dst, const u16* src, int stride, int tid) {
#pragma unroll
  for (int i = 0; i < 2; ++i) {
    int idx = tid + i * 256;
    int r = idx >> 3, c = idx & 7;
    u32x4 v = *(const u32x4*)(src + (size_t)r * stride + c * 8);
    *(u32x4*)(dst + r * 64 + ((c ^ (r & 7)) * 8)) = v;
  }
}

__device__ __forceinline__ bf16x8 ld_frag64(const u16* lds, int rowbase, int chunkbase, int l) {
  int row = rowbase + (l & 15);
  int chunk = chunkbase + (l >> 4);
  int slot = chunk ^ (row & 7);
  return __builtin_bit_cast(bf16x8, *(const u32x4*)(lds + row * 64 + slot * 8));
}

// compute 64x64 S-tile fragments for this wave's 16 q-rows; scale + causal mask
__device__ __forceinline__ void compute_S(const u16* ks, bf16x8 qA0, bf16x8 qA1, int l, int t,
                                          int qt, int qrow0, f32x4 s[4]) {
  f32x4 zf = {0.f, 0.f, 0.f, 0.f};
#pragma unroll
  for (int nf = 0; nf < 4; ++nf) {
    f32x4 z = zf;
    z = mfma16(qA0, ld_frag64(ks, nf * 16, 0, l), z);
    z = mfma16(qA1, ld_frag64(ks, nf * 16, 4, l), z);
    s[nf] = z;
  }
  const float sc = 0.03125f;  // 1/sqrt(D)=1/32
#pragma unroll
  for (int nf = 0; nf < 4; ++nf)
#pragma unroll
    for (int r = 0; r < 4; ++r) {
      float v = s[nf][r] * sc;
      if (t == qt) {
        int key = t * 64 + nf * 16 + (l & 15);
        int qr = qrow0 + (l >> 4) * 4 + r;
        if (key > qr) v = -3.402823466e38f;
      }
      s[nf][r] = v;
    }
}

// ---------- fused attention: per (64-row q-tile, head); two-pass online softmax ----------
__global__ __launch_bounds__(256) void attn_kernel(const u16* __restrict__ qb,
                                                   const u16* __restrict__ kkb,
                                                   const u16* __restrict__ kmb,
                                                   const u16* __restrict__ vkT,
                                                   const u16* __restrict__ vmT,
                                                   float* __restrict__ scores,
                                                   u16* __restrict__ ao) {
  const int qt = 31 - (int)blockIdx.x;  // big tiles dispatch first (tail balance)
  const int h = blockIdx.y;
  const int tid = threadIdx.x, w = tid >> 6, l = tid & 63;
  __shared__ u16 qs[64 * 64], ks[64 * 64], vs[64 * 64], ps[64 * 64];

  stage64(qs, qb + (size_t)(qt * 64) * D_ + h * HD_, D_, tid);
  __syncthreads();
  bf16x8 qA0 = ld_frag64(qs, w * 16, 0, l);
  bf16x8 qA1 = ld_frag64(qs, w * 16, 4, l);

  float m[4], ls[4];
#pragma unroll
  for (int r = 0; r < 4; ++r) { m[r] = -__builtin_inff(); ls[r] = 0.f; }

  const int nt = qt + 1;
  const int qrow0 = qt * 64 + w * 16;

  // ---- pass 1: stats over know then mlp halves (joint softmax) ----
  for (int hf = 0; hf < 2; ++hf) {
    const u16* kb = hf ? kmb : kkb;
    for (int t = 0; t < nt; ++t) {
      __syncthreads();
      stage64(ks, kb + (size_t)(t * 64) * D_ + h * HD_, D_, tid);
      __syncthreads();
      f32x4 s[4];
      compute_S(ks, qA0, qA1, l, t, qt, qrow0, s);
#pragma unroll
      for (int r = 0; r < 4; ++r) {
        float tm = fmaxf(fmaxf(s[0][r], s[1][r]), fmaxf(s[2][r], s[3][r]));
#pragma unroll
        for (int off = 1; off < 16; off <<= 1) tm = fmaxf(tm, __shfl_xor(tm, off, 64));
        float mn = fmaxf(m[r], tm);
        float tsum = expf(s[0][r] - mn) + expf(s[1][r] - mn) + expf(s[2][r] - mn) +
                     expf(s[3][r] - mn);
#pragma unroll
        for (int off = 1; off < 16; off <<= 1) tsum += __shfl_xor(tsum, off, 64);
        ls[r] = ls[r] * expf(m[r] - mn) + tsum;
        m[r] = mn;
      }
    }
  }
  float inv[4];
#pragma unroll
  for (int r = 0; r < 4; ++r) inv[r] = 1.0f / ls[r];

  f32x4 zf = {0.f, 0.f, 0.f, 0.f};
  f32x4 o[4];
#pragma unroll
  for (int nf = 0; nf < 4; ++nf) o[nf] = zf;

  // ---- pass 2: recompute S, normalize, write p, accumulate PV ----
  for (int hf = 0; hf < 2; ++hf) {
    const u16* kb = hf ? kmb : kkb;
    const u16* vb = hf ? vmT : vkT;
    for (int t = 0; t < nt; ++t) {
      __syncthreads();
      stage64(ks, kb + (size_t)(t * 64) * D_ + h * HD_, D_, tid);
      stage64(vs, vb + (size_t)(h * HD_) * S_ + t * 64, S_, tid);
      __syncthreads();
      f32x4 s[4];
      compute_S(ks, qA0, qA1, l, t, qt, qrow0, s);
#pragma unroll
      for (int nf = 0; nf < 4; ++nf)
#pragma unroll
        for (int r = 0; r < 4; ++r) {
          int qr = qrow0 + (l >> 4) * 4 + r;
          float p = expf(s[nf][r] - m[r]) * inv[r];
          int col = hf * S_ + t * 64 + nf * 16 + (l & 15);
          scores[((size_t)h * S_ + qr) * (2 * S_) + col] = p;
          int prow = w * 16 + (l >> 4) * 4 + r;
          int pcol = nf * 16 + (l & 15);
          ps[prow * 64 + ((pcol >> 3) ^ (prow & 7)) * 8 + (pcol & 7)] = f2bf(p);
        }
      // PV: each wave consumes only the ps rows it wrote (no barrier needed)
#pragma unroll
      for (int kk2 = 0; kk2 < 2; ++kk2) {
        bf16x8 pa = ld_frag64(ps, w * 16, kk2 * 4, l);
#pragma unroll
        for (int nf = 0; nf < 4; ++nf)
          o[nf] = mfma16(pa, ld_frag64(vs, nf * 16, kk2 * 4, l), o[nf]);
      }
    }
  }
#pragma unroll
  for (int nf = 0; nf < 4; ++nf)
#pragma unroll
    for (int r = 0; r < 4; ++r) {
      int row = qt * 64 + w * 16 + (l >> 4) * 4 + r;
      int col = h * HD_ + nf * 16 + (l & 15);
      ao[(size_t)row * D_ + col] = f2bf(o[nf][r]);
    }
}

// ---------- zero-fill the tile-aligned causal complement of concat_scores ----------
__global__ __launch_bounds__(256) void zerofill_kernel(float* __restrict__ scores) {
  int h = blockIdx.x >> 5, qt = blockIdx.x & 31;
  int Z = S_ - (qt + 1) * 64;
  if (Z <= 0) return;
  int vpH = Z >> 2;
  int rowvecs = vpH * 2;
  int total = 64 * rowvecs;
  f32x4 zero = {0.f, 0.f, 0.f, 0.f};
  for (int i = threadIdx.x; i < total; i += 256) {
    int row = i / rowvecs;
    int rem = i - row * rowvecs;
    int hf = rem >= vpH;
    int cv = hf ? rem - vpH : rem;
    int col = (qt + 1) * 64 + hf * S_ + cv * 4;
    *(f32x4*)(scores + ((size_t)h * S_ + qt * 64 + row) * (2 * S_) + col) = zero;
  }
}

extern "C" void kernel_launch(void* const* d_in, const int* in_sizes, int n_in, void* d_out,
                              int out_size, void* d_ws, size_t ws_size, hipStream_t stream) {
  const float* hs = (const float*)d_in[0];
  const float* kn = (const float*)d_in[1];
  const float* Wq = (const float*)d_in[2];
  const float* Wkk = (const float*)d_in[3];
  const float* Wkm = (const float*)d_in[4];
  const float* Wvk = (const float*)d_in[5];
  const float* Wvm = (const float*)d_in[6];
  const float* Wo = (const float*)d_in[7];
  float* out = (float*)d_out;
  float* scores = out + (size_t)S_ * D_;

  const size_t M2 = (size_t)S_ * D_;  // 2M elems
  u16* ws = (u16*)d_ws;               // needs ~50 MB
  u16* hs_bf = ws;
  u16* kn_bf = hs_bf + M2;
  u16* WqT = kn_bf + M2;      // [1024][2048]
  u16* WkkT = WqT + M2;       // [1024][1024]
  u16* WkmT = WkkT + M2 / 2;
  u16* WvkT = WkmT + M2 / 2;
  u16* WvmT = WvkT + M2 / 2;
  u16* WoT = WvmT + M2 / 2;
  u16* qb = WoT + M2 / 2;
  u16* kkb = qb + M2;
  u16* kmb = kkb + M2;
  u16* vkb = kmb + M2;
  u16* vmb = vkb + M2;
  u16* vkT = vmb + M2;  // [1024][2048] = per-head [h][hd][s]
  u16* vmT = vkT + M2;
  u16* aob = vmT + M2;

  int n4 = (int)(M2 / 4);
  cast_kernel<<<(n4 + 255) / 256, 256, 0, stream>>>(hs, hs_bf, n4);
  cast_kernel<<<(n4 + 255) / 256, 256, 0, stream>>>(kn, kn_bf, n4);
  castT_kernel<<<dim3(32, 64), 256, 0, stream>>>(Wq, WqT, 2048, 1024);
  castT_kernel<<<dim3(32, 32), 256, 0, stream>>>(Wkk, WkkT, 1024, 1024);
  castT_kernel<<<dim3(32, 32), 256, 0, stream>>>(Wkm, WkmT, 1024, 1024);
  castT_kernel<<<dim3(32, 32), 256, 0, stream>>>(Wvk, WvkT, 1024, 1024);
  castT_kernel<<<dim3(32, 32), 256, 0, stream>>>(Wvm, WvmT, 1024, 1024);
  castT_kernel<<<dim3(32, 32), 256, 0, stream>>>(Wo, WoT, 1024, 1024);

  dim3 gg(8, 16);
  gemm_kernel<0><<<gg, 256, 0, stream>>>(hs_bf, kn_bf, 1024, WqT, qb, 2048);
  gemm_kernel<0><<<gg, 256, 0, stream>>>(kn_bf, kn_bf, 1024, WkkT, kkb, 1024);
  gemm_kernel<0><<<gg, 256, 0, stream>>>(hs_bf, hs_bf, 1024, WkmT, kmb, 1024);
  gemm_kernel<0><<<gg, 256, 0, stream>>>(kn_bf, kn_bf, 1024, WvkT, vkb, 1024);
  gemm_kernel<0><<<gg, 256, 0, stream>>>(hs_bf, hs_bf, 1024, WvmT, vmb, 1024);

  transpose_bf16<<<dim3(32, 64), 256, 0, stream>>>(vkb, vkT, 2048, 1024);
  transpose_bf16<<<dim3(32, 64), 256, 0, stream>>>(vmb, vmT, 2048, 1024);

  zerofill_kernel<<<512, 256, 0, stream>>>(scores);
  attn_kernel<<<dim3(32, 16), 256, 0, stream>>>(qb, kkb, kmb, vkT, vmT, scores, aob);

  gemm_kernel<1><<<gg, 256, 0, stream>>>(aob, aob, 1024, WoT, out, 1024);
}

// Round 2
// 401.816 us; speedup vs baseline: 1.4436x; 1.4436x over previous
//
#include <hip/hip_runtime.h>

typedef unsigned short u16;
typedef float f32x4 __attribute__((ext_vector_type(4)));
typedef __bf16 bf16x8 __attribute__((ext_vector_type(8)));
typedef unsigned int u32x4 __attribute__((ext_vector_type(4)));
typedef u16 u16x4 __attribute__((ext_vector_type(4)));

#define S_ 2048
#define D_ 1024
#define H_ 16
#define HD_ 64
#define KS2 2048  // fused KV buffer row stride

__device__ __forceinline__ u16 f2bf(float f) {
  unsigned int u = __builtin_bit_cast(unsigned int, f);
  u += 0x7fffu + ((u >> 16) & 1u);
  return (u16)(u >> 16);
}

__device__ __forceinline__ f32x4 mfma16(bf16x8 a, bf16x8 b, f32x4 c) {
  return __builtin_amdgcn_mfma_f32_16x16x32_bf16(a, b, c, 0, 0, 0);
}

// 2^x via v_exp_f32 (s_nop covers the TRANS->VALU hazard window)
__device__ __forceinline__ float ex2(float x) {
  float r;
  asm("v_exp_f32 %0, %1\n\ts_nop 1" : "=v"(r) : "v"(x));
  return r;
}

// async global->LDS, 16B per lane. LDS dest must be linear in lane order.
__device__ __forceinline__ void gld_lds16(const u16* g, u16* l) {
  __builtin_amdgcn_global_load_lds((const __attribute__((address_space(1))) void*)g,
                                   (__attribute__((address_space(3))) void*)l, 16, 0, 0);
}

// ---------- cast fp32 -> bf16 (vectorized) ----------
__global__ void cast_kernel(const float* __restrict__ src, u16* __restrict__ dst, int n4) {
  int i = blockIdx.x * 256 + threadIdx.x;
  if (i >= n4) return;
  f32x4 v = *(const f32x4*)(src + (size_t)i * 4);
  u16x4 o;
  o[0] = f2bf(v[0]); o[1] = f2bf(v[1]); o[2] = f2bf(v[2]); o[3] = f2bf(v[3]);
  *(u16x4*)(dst + (size_t)i * 4) = o;
}

// ---------- cast + transpose fp32 W[R][C] -> bf16 WT[C][R] ----------
__global__ __launch_bounds__(256) void castT_kernel(const float* __restrict__ W,
                                                    u16* __restrict__ WT, int R, int Cn) {
  __shared__ float tile[32][33];
  int tx = threadIdx.x & 31, ty = threadIdx.x >> 5;
  int bc = blockIdx.x, br = blockIdx.y;
#pragma unroll
  for (int i = 0; i < 4; ++i)
    tile[ty + i * 8][tx] = W[(size_t)(br * 32 + ty + i * 8) * Cn + bc * 32 + tx];
  __syncthreads();
#pragma unroll
  for (int i = 0; i < 4; ++i)
    WT[(size_t)(bc * 32 + ty + i * 8) * R + br * 32 + tx] = f2bf(tile[tx][ty + i * 8]);
}

// ---------- bf16 transpose V[2048][1024 cols @ stride ldv] -> VT[1024][2048] ----------
__global__ __launch_bounds__(256) void transpose_bf16(const u16* __restrict__ V,
                                                      u16* __restrict__ VT, int ldv) {
  __shared__ u16 tile[32][33];
  int tx = threadIdx.x & 31, ty = threadIdx.x >> 5;
  int bc = blockIdx.x, br = blockIdx.y;
#pragma unroll
  for (int i = 0; i < 4; ++i)
    tile[ty + i * 8][tx] = V[(size_t)(br * 32 + ty + i * 8) * ldv + bc * 32 + tx];
  __syncthreads();
#pragma unroll
  for (int i = 0; i < 4; ++i)
    VT[(size_t)(bc * 32 + ty + i * 8) * S_ + br * 32 + tx] = tile[tx][ty + i * 8];
}

// ---------- GEMM: C[M][N] = A[2048][K] * BT[n][k]; 128x128 tile, BK=32, 4 waves ----------
// A optionally concatenated (A0|A1) along K at ksplit; A row stride fixed D_.
// Staging via global_load_lds (linear LDS dest, pre-swizzled source).
template <int CF32>
__global__ __launch_bounds__(256) void gemm_kernel(const u16* __restrict__ A0,
                                                   const u16* __restrict__ A1, int ksplit,
                                                   const u16* __restrict__ BT,
                                                   void* __restrict__ Cp, int K, int ldc) {
  __shared__ u16 As[128 * 32];
  __shared__ u16 Bs[128 * 32];
  const int tid = threadIdx.x, l = tid & 63, w = tid >> 6;
  const int wm = w >> 1, wn = w & 1;
  const int bm = blockIdx.y, bn = blockIdx.x;
  f32x4 zf = {0.f, 0.f, 0.f, 0.f};
  f32x4 acc[4][4];
#pragma unroll
  for (int mi = 0; mi < 4; ++mi)
#pragma unroll
    for (int ni = 0; ni < 4; ++ni) acc[mi][ni] = zf;

  for (int k0 = 0; k0 < K; k0 += 32) {
    __syncthreads();  // readers done with LDS
#pragma unroll
    for (int i = 0; i < 2; ++i) {  // A: 128 rows x 4 chunks(16B), swizzled source
      int idx = tid + i * 256, r = idx >> 2, c = idx & 3;
      int sc = c ^ ((r >> 1) & 3);
      int k = k0 + sc * 8;
      const u16* src = (k < ksplit) ? (A0 + (size_t)(bm * 128 + r) * D_ + k)
                                    : (A1 + (size_t)(bm * 128 + r) * D_ + (k - ksplit));
      gld_lds16(src, As + idx * 8);
    }
#pragma unroll
    for (int i = 0; i < 2; ++i) {  // B
      int idx = tid + i * 256, r = idx >> 2, c = idx & 3;
      int sc = c ^ ((r >> 1) & 3);
      gld_lds16(BT + (size_t)(bn * 128 + r) * K + k0 + sc * 8, Bs + idx * 8);
    }
    __syncthreads();  // drain vmcnt -> tiles ready
    bf16x8 af[4], bfr[4];
#pragma unroll
    for (int mi = 0; mi < 4; ++mi) {
      int row = wm * 64 + mi * 16 + (l & 15);
      int slot = (l >> 4) ^ ((row >> 1) & 3);
      af[mi] = __builtin_bit_cast(bf16x8, *(const u32x4*)(As + row * 32 + slot * 8));
    }
#pragma unroll
    for (int ni = 0; ni < 4; ++ni) {
      int row = wn * 64 + ni * 16 + (l & 15);
      int slot = (l >> 4) ^ ((row >> 1) & 3);
      bfr[ni] = __builtin_bit_cast(bf16x8, *(const u32x4*)(Bs + row * 32 + slot * 8));
    }
#pragma unroll
    for (int mi = 0; mi < 4; ++mi)
#pragma unroll
      for (int ni = 0; ni < 4; ++ni) acc[mi][ni] = mfma16(af[mi], bfr[ni], acc[mi][ni]);
  }
#pragma unroll
  for (int mi = 0; mi < 4; ++mi)
#pragma unroll
    for (int ni = 0; ni < 4; ++ni)
#pragma unroll
      for (int r = 0; r < 4; ++r) {
        int row = bm * 128 + wm * 64 + mi * 16 + (l >> 4) * 4 + r;
        int col = bn * 128 + wn * 64 + ni * 16 + (l & 15);
        if (CF32)
          ((float*)Cp)[(size_t)row * ldc + col] = acc[mi][ni][r];
        else
          ((u16*)Cp)[(size_t)row * ldc + col] = f2bf(acc[mi][ni][r]);
      }
}

// ---------- async 64x64 bf16 tile stage (XOR-swizzled via source) ----------
__device__ __forceinline__ void stage_async64(u16* dst, const u16* src, int stride, int tid) {
  int w = tid >> 6, l = tid & 63;
#pragma unroll
  for (int j = 0; j < 4; ++j) {
    int ci = (w * 4 + j) * 64 + l;  // 16B chunk index 0..511, linear per wave
    int r = ci >> 3, c = ci & 7;
    int sc = c ^ (r & 7);
    gld_lds16(src + (size_t)r * stride + sc * 8, dst + ci * 8);
  }
}

__device__ __forceinline__ bf16x8 ld_frag64(const u16* lds, int rowbase, int chunkbase, int l) {
  int row = rowbase + (l & 15);
  int chunk = chunkbase + (l >> 4);
  int slot = chunk ^ (row & 7);
  return __builtin_bit_cast(bf16x8, *(const u32x4*)(lds + row * 64 + slot * 8));
}

// compute 64-key S fragments for this wave's 16 q-rows; scale(+log2e) + causal mask
__device__ __forceinline__ void compute_S(const u16* ks, bf16x8 qA0, bf16x8 qA1, int l,
                                          int domask, int tbase, int qr0, f32x4 s[4]) {
  f32x4 zf = {0.f, 0.f, 0.f, 0.f};
#pragma unroll
  for (int nf = 0; nf < 4; ++nf) {
    f32x4 z = zf;
    z = mfma16(qA0, ld_frag64(ks, nf * 16, 0, l), z);
    z = mfma16(qA1, ld_frag64(ks, nf * 16, 4, l), z);
    s[nf] = z;
  }
  const float sc2 = 0.04508422f;  // log2(e)/32
#pragma unroll
  for (int nf = 0; nf < 4; ++nf)
#pragma unroll
    for (int r = 0; r < 4; ++r) {
      float v = s[nf][r] * sc2;
      if (domask) {
        int key = tbase + nf * 16 + (l & 15);
        int qr = qr0 + (l >> 4) * 4 + r;
        if (key > qr) v = -1e30f;
      }
      s[nf][r] = v;
    }
}

// ---------- fused attention: block per (32-row q-tile, head); 2 waves ----------
__global__ __launch_bounds__(128) void attn_kernel(const u16* __restrict__ qb,
                                                   const u16* __restrict__ kvk,
                                                   const u16* __restrict__ kvm,
                                                   const u16* __restrict__ vkT,
                                                   const u16* __restrict__ vmT,
                                                   float* __restrict__ scores,
                                                   u16* __restrict__ ao) {
  const int fid = blockIdx.x;
  const int xcd = fid & 7, ixd = fid >> 3;
  const int g = xcd * 128 + ixd;  // 2 heads per XCD -> K/V L2-resident
  const int h = g >> 6;
  const int gq = g & 63;
  const int qt = (gq & 1) ? (gq >> 1) : (63 - (gq >> 1));  // pair large+small
  const int tid = threadIdx.x, w = tid >> 6, l = tid & 63;
  const int nt = (qt >> 1) + 1;  // 64-key tiles per half
  const int NT = 2 * nt;
  const int qrow0 = qt * 32;

  __shared__ u16 qs[32 * 64];
  __shared__ u16 ks[2][64 * 64];
  __shared__ u16 vs[2][64 * 64];
  __shared__ u16 ps[32 * 64];

  auto kptr = [&](int it) {
    int hf = it >= nt;
    int t = it - (hf ? nt : 0);
    const u16* kb = hf ? kvm : kvk;
    return kb + (size_t)(t * 64) * KS2 + h * HD_;
  };
  auto vptr = [&](int it) {
    int hf = it >= nt;
    int t = it - (hf ? nt : 0);
    const u16* vb = hf ? vmT : vkT;
    return vb + (size_t)(h * HD_) * S_ + t * 64;
  };

  // stage Q (sync, swizzled write)
#pragma unroll
  for (int i = 0; i < 2; ++i) {
    int idx = tid + i * 128;  // 0..255 chunks
    int r = idx >> 3, c = idx & 7;
    u32x4 v = *(const u32x4*)(qb + (size_t)(qrow0 + r) * D_ + h * HD_ + c * 8);
    *(u32x4*)(qs + r * 64 + ((c ^ (r & 7)) * 8)) = v;
  }
  __syncthreads();
  bf16x8 qA0 = ld_frag64(qs, w * 16, 0, l);
  bf16x8 qA1 = ld_frag64(qs, w * 16, 4, l);

  float m[4], lsum[4];
#pragma unroll
  for (int r = 0; r < 4; ++r) { m[r] = -1e30f; lsum[r] = 0.f; }

  // ---- pass 1: softmax stats (double-buffered async K staging) ----
  stage_async64(ks[0], kptr(0), KS2, tid);
  __syncthreads();
  int cur = 0;
  for (int it = 0; it < NT; ++it) {
    if (it + 1 < NT) stage_async64(ks[cur ^ 1], kptr(it + 1), KS2, tid);
    int domask = (it == nt - 1) || (it == NT - 1);
    int hf = it >= nt;
    int tbase = (it - (hf ? nt : 0)) * 64;
    f32x4 s[4];
    compute_S(ks[cur], qA0, qA1, l, domask, tbase, qrow0 + w * 16, s);
#pragma unroll
    for (int r = 0; r < 4; ++r) {
      float tm = fmaxf(fmaxf(s[0][r], s[1][r]), fmaxf(s[2][r], s[3][r]));
#pragma unroll
      for (int off = 1; off < 16; off <<= 1) tm = fmaxf(tm, __shfl_xor(tm, off, 64));
      float mn = fmaxf(m[r], tm);
      float tsum = ex2(s[0][r] - mn) + ex2(s[1][r] - mn) + ex2(s[2][r] - mn) + ex2(s[3][r] - mn);
#pragma unroll
      for (int off = 1; off < 16; off <<= 1) tsum += __shfl_xor(tsum, off, 64);
      lsum[r] = lsum[r] * ex2(m[r] - mn) + tsum;
      m[r] = mn;
    }
    __syncthreads();
    cur ^= 1;
  }
  float inv[4];
#pragma unroll
  for (int r = 0; r < 4; ++r) inv[r] = 1.0f / lsum[r];

  f32x4 zf = {0.f, 0.f, 0.f, 0.f};
  f32x4 o[4];
#pragma unroll
  for (int nf = 0; nf < 4; ++nf) o[nf] = zf;

  // ---- pass 2: recompute S, normalize, write p, accumulate PV ----
  stage_async64(ks[0], kptr(0), KS2, tid);
  stage_async64(vs[0], vptr(0), S_, tid);
  __syncthreads();
  cur = 0;
  for (int it = 0; it < NT; ++it) {
    if (it + 1 < NT) {
      stage_async64(ks[cur ^ 1], kptr(it + 1), KS2, tid);
      stage_async64(vs[cur ^ 1], vptr(it + 1), S_, tid);
    }
    int domask = (it == nt - 1) || (it == NT - 1);
    int hf = it >= nt;
    int tbase = (it - (hf ? nt : 0)) * 64;
    f32x4 s[4];
    compute_S(ks[cur], qA0, qA1, l, domask, tbase, qrow0 + w * 16, s);
#pragma unroll
    for (int nf = 0; nf < 4; ++nf)
#pragma unroll
      for (int r = 0; r < 4; ++r) {
        int qr = qrow0 + w * 16 + (l >> 4) * 4 + r;
        float p = ex2(s[nf][r] - m[r]) * inv[r];
        int col = hf * S_ + tbase + nf * 16 + (l & 15);
        scores[((size_t)h * S_ + qr) * (2 * S_) + col] = p;
        int prow = w * 16 + (l >> 4) * 4 + r;
        int pcol = nf * 16 + (l & 15);
        ps[prow * 64 + ((pcol >> 3) ^ (prow & 7)) * 8 + (pcol & 7)] = f2bf(p);
      }
    // PV: each wave consumes only the ps rows it wrote (no extra barrier)
#pragma unroll
    for (int kk2 = 0; kk2 < 2; ++kk2) {
      bf16x8 pa = ld_frag64(ps, w * 16, kk2 * 4, l);
#pragma unroll
      for (int nf = 0; nf < 4; ++nf)
        o[nf] = mfma16(pa, ld_frag64(vs[cur], nf * 16, kk2 * 4, l), o[nf]);
    }
    __syncthreads();
    cur ^= 1;
  }
#pragma unroll
  for (int nf = 0; nf < 4; ++nf)
#pragma unroll
    for (int r = 0; r < 4; ++r) {
      int row = qrow0 + w * 16 + (l >> 4) * 4 + r;
      int col = h * HD_ + nf * 16 + (l & 15);
      ao[(size_t)row * D_ + col] = f2bf(o[nf][r]);
    }
}

// ---------- zero-fill the tile-aligned causal complement of concat_scores ----------
__global__ __launch_bounds__(256) void zerofill_kernel(float* __restrict__ scores) {
  int h = blockIdx.x >> 5, qt = blockIdx.x & 31;
  int Z = S_ - (qt + 1) * 64;
  if (Z <= 0) return;
  int vpH = Z >> 2;
  int rowvecs = vpH * 2;
  int total = 64 * rowvecs;
  f32x4 zero = {0.f, 0.f, 0.f, 0.f};
  for (int i = threadIdx.x; i < total; i += 256) {
    int row = i / rowvecs;
    int rem = i - row * rowvecs;
    int hf = rem >= vpH;
    int cv = hf ? rem - vpH : rem;
    int col = (qt + 1) * 64 + hf * S_ + cv * 4;
    *(f32x4*)(scores + ((size_t)h * S_ + qt * 64 + row) * (2 * S_) + col) = zero;
  }
}

extern "C" void kernel_launch(void* const* d_in, const int* in_sizes, int n_in, void* d_out,
                              int out_size, void* d_ws, size_t ws_size, hipStream_t stream) {
  const float* hs = (const float*)d_in[0];
  const float* kn = (const float*)d_in[1];
  const float* Wq = (const float*)d_in[2];
  const float* Wkk = (const float*)d_in[3];
  const float* Wkm = (const float*)d_in[4];
  const float* Wvk = (const float*)d_in[5];
  const float* Wvm = (const float*)d_in[6];
  const float* Wo = (const float*)d_in[7];
  float* out = (float*)d_out;
  float* scores = out + (size_t)S_ * D_;

  const size_t M2 = (size_t)S_ * D_;  // 2M elems
  u16* ws = (u16*)d_ws;               // ~54 MB
  u16* hs_bf = ws;
  u16* kn_bf = hs_bf + M2;
  u16* WqT = kn_bf + M2;        // [1024][2048]
  u16* WkvkT = WqT + M2;        // [2048][1024]: rows 0-1023 Wkk^T, 1024-2047 Wvk^T
  u16* WkvmT = WkvkT + M2;      // same for mlp
  u16* WoT = WkvmT + M2;        // [1024][1024]
  u16* qb = WoT + M2 / 2;       // [2048][1024]
  u16* kvk = qb + M2;           // [2048][2048]: cols 0-1023 K_know, 1024-2047 V_know
  u16* kvm = kvk + 2 * M2;      // same for mlp
  u16* vkT = kvm + 2 * M2;      // [1024][2048] per-head [h][hd][s]
  u16* vmT = vkT + M2;
  u16* aob = vmT + M2;

  int n4 = (int)(M2 / 4);
  cast_kernel<<<(n4 + 255) / 256, 256, 0, stream>>>(hs, hs_bf, n4);
  cast_kernel<<<(n4 + 255) / 256, 256, 0, stream>>>(kn, kn_bf, n4);
  castT_kernel<<<dim3(32, 64), 256, 0, stream>>>(Wq, WqT, 2048, 1024);
  castT_kernel<<<dim3(32, 32), 256, 0, stream>>>(Wkk, WkvkT, 1024, 1024);
  castT_kernel<<<dim3(32, 32), 256, 0, stream>>>(Wvk, WkvkT + M2 / 2, 1024, 1024);
  castT_kernel<<<dim3(32, 32), 256, 0, stream>>>(Wkm, WkvmT, 1024, 1024);
  castT_kernel<<<dim3(32, 32), 256, 0, stream>>>(Wvm, WkvmT + M2 / 2, 1024, 1024);
  castT_kernel<<<dim3(32, 32), 256, 0, stream>>>(Wo, WoT, 1024, 1024);

  const int BIG = 1 << 30;
  gemm_kernel<0><<<dim3(16, 16), 256, 0, stream>>>(kn_bf, kn_bf, BIG, WkvkT, kvk, 1024, 2048);
  gemm_kernel<0><<<dim3(16, 16), 256, 0, stream>>>(hs_bf, hs_bf, BIG, WkvmT, kvm, 1024, 2048);
  gemm_kernel<0><<<dim3(8, 16), 256, 0, stream>>>(hs_bf, kn_bf, 1024, WqT, qb, 2048, 1024);

  transpose_bf16<<<dim3(32, 64), 256, 0, stream>>>(kvk + 1024, vkT, 2048);
  transpose_bf16<<<dim3(32, 64), 256, 0, stream>>>(kvm + 1024, vmT, 2048);

  zerofill_kernel<<<512, 256, 0, stream>>>(scores);
  attn_kernel<<<1024, 128, 0, stream>>>(qb, kvk, kvm, vkT, vmT, scores, aob);

  gemm_kernel<1><<<dim3(8, 16), 256, 0, stream>>>(aob, aob, BIG, WoT, out, 1024, 1024);
}

// Round 3
// 299.248 us; speedup vs baseline: 1.9384x; 1.3428x over previous
//
#include <hip/hip_runtime.h>

typedef unsigned short u16;
typedef float f32x4 __attribute__((ext_vector_type(4)));
typedef __bf16 bf16x8 __attribute__((ext_vector_type(8)));
typedef unsigned int u32x4 __attribute__((ext_vector_type(4)));
typedef u16 u16x4 __attribute__((ext_vector_type(4)));

#define S_ 2048
#define D_ 1024
#define H_ 16
#define HD_ 64
#define KS2 2048  // fused KV buffer row stride

#define WAITV(N) asm volatile("s_waitcnt vmcnt(" #N ")" ::: "memory")
#define BAR() __builtin_amdgcn_s_barrier()
#define SFENCE() __builtin_amdgcn_sched_barrier(0)

__device__ __forceinline__ u16 f2bf(float f) {
  unsigned int u = __builtin_bit_cast(unsigned int, f);
  u += 0x7fffu + ((u >> 16) & 1u);
  return (u16)(u >> 16);
}

__device__ __forceinline__ f32x4 mfma16(bf16x8 a, bf16x8 b, f32x4 c) {
  return __builtin_amdgcn_mfma_f32_16x16x32_bf16(a, b, c, 0, 0, 0);
}

// 2^x via v_exp_f32 (s_nop covers the TRANS->VALU hazard window)
__device__ __forceinline__ float ex2(float x) {
  float r;
  asm("v_exp_f32 %0, %1\n\ts_nop 1" : "=v"(r) : "v"(x));
  return r;
}

// async global->LDS, 16B per lane. LDS dest must be linear in lane order.
__device__ __forceinline__ void gld_lds16(const u16* g, u16* l) {
  __builtin_amdgcn_global_load_lds((const __attribute__((address_space(1))) void*)g,
                                   (__attribute__((address_space(3))) void*)l, 16, 0, 0);
}

// ---------- cast both fp32 inputs -> bf16 (one launch) ----------
__global__ void cast_all(const float* __restrict__ a, const float* __restrict__ b,
                         u16* __restrict__ da, u16* __restrict__ db, int n4) {
  int i = blockIdx.x * 256 + threadIdx.x;
  const float* s;
  u16* d;
  int j;
  if (i < n4) { s = a; d = da; j = i; }
  else { j = i - n4; if (j >= n4) return; s = b; d = db; }
  f32x4 v = *(const f32x4*)(s + (size_t)j * 4);
  u16x4 o;
  o[0] = f2bf(v[0]); o[1] = f2bf(v[1]); o[2] = f2bf(v[2]); o[3] = f2bf(v[3]);
  *(u16x4*)(d + (size_t)j * 4) = o;
}

// ---------- cast + transpose all 6 weights (one launch) ----------
__global__ __launch_bounds__(256) void castT_all(
    const float* __restrict__ Wq, const float* __restrict__ Wkk, const float* __restrict__ Wvk,
    const float* __restrict__ Wkm, const float* __restrict__ Wvm, const float* __restrict__ Wo,
    u16* __restrict__ WqT, u16* __restrict__ WkvkT, u16* __restrict__ WkvmT,
    u16* __restrict__ WoT) {
  __shared__ float tile[32][33];
  int y = blockIdx.y;
  const float* W;
  u16* WT;
  int R, br;
  const size_t HM = (size_t)1024 * 1024;
  if (y < 64) { W = Wq; WT = WqT; R = 2048; br = y; }
  else {
    R = 1024; br = y & 31;
    switch ((y - 64) >> 5) {
      case 0: W = Wkk; WT = WkvkT; break;
      case 1: W = Wvk; WT = WkvkT + HM; break;
      case 2: W = Wkm; WT = WkvmT; break;
      case 3: W = Wvm; WT = WkvmT + HM; break;
      default: W = Wo; WT = WoT; break;
    }
  }
  int tx = threadIdx.x & 31, ty = threadIdx.x >> 5;
  int bc = blockIdx.x;
#pragma unroll
  for (int i = 0; i < 4; ++i)
    tile[ty + i * 8][tx] = W[(size_t)(br * 32 + ty + i * 8) * 1024 + bc * 32 + tx];
  __syncthreads();
#pragma unroll
  for (int i = 0; i < 4; ++i)
    WT[(size_t)(bc * 32 + ty + i * 8) * R + br * 32 + tx] = f2bf(tile[tx][ty + i * 8]);
}

// ---------- bf16 transpose: both V halves (z selects) ----------
__global__ __launch_bounds__(256) void transpose2(const u16* __restrict__ v0,
                                                  const u16* __restrict__ v1,
                                                  u16* __restrict__ t0, u16* __restrict__ t1) {
  __shared__ u16 tile[32][33];
  const u16* V = blockIdx.z ? v1 : v0;
  u16* VT = blockIdx.z ? t1 : t0;
  int tx = threadIdx.x & 31, ty = threadIdx.x >> 5;
  int bc = blockIdx.x, br = blockIdx.y;
#pragma unroll
  for (int i = 0; i < 4; ++i)
    tile[ty + i * 8][tx] = V[(size_t)(br * 32 + ty + i * 8) * 2048 + bc * 32 + tx];
  __syncthreads();
#pragma unroll
  for (int i = 0; i < 4; ++i)
    VT[(size_t)(bc * 32 + ty + i * 8) * S_ + br * 32 + tx] = tile[tx][ty + i * 8];
}

// ---------- GEMM body: C[128bm..][128bn..] = A[2048][K] * BT[n][k] ----------
// Double-buffered LDS + counted vmcnt (4 gld_lds/thread/tile, in-order retire).
template <int CF32>
__device__ __forceinline__ void gemm_body(const u16* A0, const u16* A1, int ksplit,
                                          const u16* BT, void* Cp, int K, int ldc, int bn,
                                          int bm) {
  __shared__ u16 As[2][128 * 32];
  __shared__ u16 Bs[2][128 * 32];
  const int tid = threadIdx.x, l = tid & 63, w = tid >> 6;
  const int wm = w >> 1, wn = w & 1;
  f32x4 zf = {0.f, 0.f, 0.f, 0.f};
  f32x4 acc[4][4];
#pragma unroll
  for (int mi = 0; mi < 4; ++mi)
#pragma unroll
    for (int ni = 0; ni < 4; ++ni) acc[mi][ni] = zf;

  auto STAGE = [&](int b, int t) {
    int k0 = t * 32;
#pragma unroll
    for (int i = 0; i < 2; ++i) {  // A: 128 rows x 4 chunks(16B), swizzled source
      int idx = tid + i * 256, r = idx >> 2, c = idx & 3;
      int sc = c ^ ((r >> 1) & 3);
      int k = k0 + sc * 8;
      const u16* src = (k < ksplit) ? (A0 + (size_t)(bm * 128 + r) * D_ + k)
                                    : (A1 + (size_t)(bm * 128 + r) * D_ + (k - ksplit));
      gld_lds16(src, As[b] + idx * 8);
    }
#pragma unroll
    for (int i = 0; i < 2; ++i) {  // B
      int idx = tid + i * 256, r = idx >> 2, c = idx & 3;
      int sc = c ^ ((r >> 1) & 3);
      gld_lds16(BT + (size_t)(bn * 128 + r) * K + k0 + sc * 8, Bs[b] + idx * 8);
    }
  };

  const int nt = K >> 5;
  STAGE(0, 0);
  int cur = 0;
  for (int t = 0; t < nt; ++t) {
    if (t + 1 < nt) { STAGE(cur ^ 1, t + 1); WAITV(4); } else { WAITV(0); }
    BAR(); SFENCE();
    bf16x8 af[4], bfr[4];
#pragma unroll
    for (int mi = 0; mi < 4; ++mi) {
      int row = wm * 64 + mi * 16 + (l & 15);
      int slot = (l >> 4) ^ ((row >> 1) & 3);
      af[mi] = __builtin_bit_cast(bf16x8, *(const u32x4*)(As[cur] + row * 32 + slot * 8));
    }
#pragma unroll
    for (int ni = 0; ni < 4; ++ni) {
      int row = wn * 64 + ni * 16 + (l & 15);
      int slot = (l >> 4) ^ ((row >> 1) & 3);
      bfr[ni] = __builtin_bit_cast(bf16x8, *(const u32x4*)(Bs[cur] + row * 32 + slot * 8));
    }
#pragma unroll
    for (int mi = 0; mi < 4; ++mi)
#pragma unroll
      for (int ni = 0; ni < 4; ++ni) acc[mi][ni] = mfma16(af[mi], bfr[ni], acc[mi][ni]);
    SFENCE(); BAR();
    cur ^= 1;
  }
#pragma unroll
  for (int mi = 0; mi < 4; ++mi)
#pragma unroll
    for (int ni = 0; ni < 4; ++ni)
#pragma unroll
      for (int r = 0; r < 4; ++r) {
        int row = bm * 128 + wm * 64 + mi * 16 + (l >> 4) * 4 + r;
        int col = bn * 128 + wn * 64 + ni * 16 + (l & 15);
        if (CF32)
          ((float*)Cp)[(size_t)row * ldc + col] = acc[mi][ni][r];
        else
          ((u16*)Cp)[(size_t)row * ldc + col] = f2bf(acc[mi][ni][r]);
      }
}

// ---------- fused projection GEMM: Q + KVknow + KVmlp in one launch ----------
__global__ __launch_bounds__(256) void proj_gemm(const u16* __restrict__ hs_bf,
                                                 const u16* __restrict__ kn_bf,
                                                 const u16* __restrict__ WqT,
                                                 const u16* __restrict__ WkvkT,
                                                 const u16* __restrict__ WkvmT,
                                                 u16* __restrict__ qb, u16* __restrict__ kvk,
                                                 u16* __restrict__ kvm) {
  int bid = blockIdx.x;                      // 640 blocks, 640%8==0
  int swz = (bid & 7) * 80 + (bid >> 3);     // XCD-contiguous chunks
  int bn = swz % 40, bm = swz / 40;
  const u16 *A0, *A1, *BT;
  u16* C;
  int K, ksplit, ldc;
  if (bn < 8) {
    A0 = hs_bf; A1 = kn_bf; ksplit = 1024; BT = WqT; C = qb; K = 2048; ldc = 1024;
  } else if (bn < 24) {
    bn -= 8; A0 = kn_bf; A1 = kn_bf; ksplit = 1 << 30; BT = WkvkT; C = kvk; K = 1024; ldc = 2048;
  } else {
    bn -= 24; A0 = hs_bf; A1 = hs_bf; ksplit = 1 << 30; BT = WkvmT; C = kvm; K = 1024; ldc = 2048;
  }
  gemm_body<0>(A0, A1, ksplit, BT, C, K, ldc, bn, bm);
}

__global__ __launch_bounds__(256) void out_gemm(const u16* __restrict__ aob,
                                                const u16* __restrict__ WoT,
                                                float* __restrict__ out) {
  gemm_body<1>(aob, aob, 1 << 30, WoT, out, 1024, 1024, blockIdx.x, blockIdx.y);
}

// ---------- async 64x64 bf16 tile stage (XOR-swizzled via source), 4 issues/thread ----------
__device__ __forceinline__ void stage_async64(u16* dst, const u16* src, int stride, int tid) {
  int w = tid >> 6, l = tid & 63;
#pragma unroll
  for (int j = 0; j < 4; ++j) {
    int ci = (w * 4 + j) * 64 + l;  // 16B chunk index 0..511, linear per wave
    int r = ci >> 3, c = ci & 7;
    int sc = c ^ (r & 7);
    gld_lds16(src + (size_t)r * stride + sc * 8, dst + ci * 8);
  }
}

__device__ __forceinline__ bf16x8 ld_frag64(const u16* lds, int rowbase, int chunkbase, int l) {
  int row = rowbase + (l & 15);
  int chunk = chunkbase + (l >> 4);
  int slot = chunk ^ (row & 7);
  return __builtin_bit_cast(bf16x8, *(const u32x4*)(lds + row * 64 + slot * 8));
}

// unswapped S: rows=q, cols=key (pass 2; feeds scores writes + ps layout)
__device__ __forceinline__ void compute_S(const u16* ks, bf16x8 qA0, bf16x8 qA1, int l,
                                          int domask, int tbase, int qr0, f32x4 s[4]) {
  f32x4 zf = {0.f, 0.f, 0.f, 0.f};
#pragma unroll
  for (int nf = 0; nf < 4; ++nf) {
    f32x4 z = zf;
    z = mfma16(qA0, ld_frag64(ks, nf * 16, 0, l), z);
    z = mfma16(qA1, ld_frag64(ks, nf * 16, 4, l), z);
    s[nf] = z;
  }
  const float sc2 = 0.04508422f;  // log2(e)/32
#pragma unroll
  for (int nf = 0; nf < 4; ++nf)
#pragma unroll
    for (int r = 0; r < 4; ++r) {
      float v = s[nf][r] * sc2;
      if (domask) {
        int key = tbase + nf * 16 + (l & 15);
        int qr = qr0 + (l >> 4) * 4 + r;
        if (key > qr) v = -1e30f;
      }
      s[nf][r] = v;
    }
}

// ---------- fused attention + causal-complement zero tail ----------
__global__ __launch_bounds__(128) void attn_kernel(const u16* __restrict__ qb,
                                                   const u16* __restrict__ kvk,
                                                   const u16* __restrict__ kvm,
                                                   const u16* __restrict__ vkT,
                                                   const u16* __restrict__ vmT,
                                                   float* __restrict__ scores,
                                                   u16* __restrict__ ao) {
  const int fid = blockIdx.x;
  const int xcd = fid & 7, ixd = fid >> 3;
  const int g = xcd * 128 + ixd;  // 2 heads per XCD -> K/V L2-resident
  const int h = g >> 6;
  const int gq = g & 63;
  const int qt = (gq & 1) ? (gq >> 1) : (63 - (gq >> 1));  // pair large+small
  const int tid = threadIdx.x, w = tid >> 6, l = tid & 63;
  const int nt = (qt >> 1) + 1;  // 64-key tiles per half
  const int NT = 2 * nt;
  const int qrow0 = qt * 32;
  const int qme = qrow0 + w * 16 + (l & 15);  // this lane's q-row (swapped layout)

  __shared__ u16 qs[32 * 64];
  __shared__ u16 ks[2][64 * 64];
  __shared__ u16 vs[2][64 * 64];
  __shared__ u16 ps[32 * 64];

  auto kptr = [&](int it) {
    int hf = it >= nt;
    int t = it - (hf ? nt : 0);
    const u16* kb = hf ? kvm : kvk;
    return kb + (size_t)(t * 64) * KS2 + h * HD_;
  };
  auto vptr = [&](int it) {
    int hf = it >= nt;
    int t = it - (hf ? nt : 0);
    const u16* vb = hf ? vmT : vkT;
    return vb + (size_t)(h * HD_) * S_ + t * 64;
  };

  // stage Q (sync, swizzled write)
#pragma unroll
  for (int i = 0; i < 2; ++i) {
    int idx = tid + i * 128;  // 256 chunks
    int r = idx >> 3, c = idx & 7;
    u32x4 v = *(const u32x4*)(qb + (size_t)(qrow0 + r) * D_ + h * HD_ + c * 8);
    *(u32x4*)(qs + r * 64 + ((c ^ (r & 7)) * 8)) = v;
  }
  __syncthreads();  // full drain: vmcnt clean for counted waits below
  bf16x8 qA0 = ld_frag64(qs, w * 16, 0, l);
  bf16x8 qA1 = ld_frag64(qs, w * 16, 4, l);

  // ---- pass 1: stats via SWAPPED QK^T (lane-local row reduce, 4 shuffles/tile) ----
  float m = -1e30f, lsum = 0.f;
  stage_async64(ks[0], kptr(0), KS2, tid);
  int cur = 0;
  for (int it = 0; it < NT; ++it) {
    if (it + 1 < NT) { stage_async64(ks[cur ^ 1], kptr(it + 1), KS2, tid); WAITV(4); }
    else { WAITV(0); }
    BAR(); SFENCE();
    int domask = (it == nt - 1) || (it == NT - 1);
    int hf = it >= nt;
    int tbase = (it - (hf ? nt : 0)) * 64;
    f32x4 zfv = {0.f, 0.f, 0.f, 0.f};
    float sv[16];
    float tm = -1e30f;
    const float sc2 = 0.04508422f;
#pragma unroll
    for (int kf = 0; kf < 4; ++kf) {
      f32x4 z = zfv;
      z = mfma16(ld_frag64(ks[cur], kf * 16, 0, l), qA0, z);
      z = mfma16(ld_frag64(ks[cur], kf * 16, 4, l), qA1, z);
#pragma unroll
      for (int r = 0; r < 4; ++r) {
        float v = z[r] * sc2;
        if (domask) {
          int key = tbase + kf * 16 + (l >> 4) * 4 + r;
          if (key > qme) v = -1e30f;
        }
        sv[kf * 4 + r] = v;
        tm = fmaxf(tm, v);
      }
    }
    tm = fmaxf(tm, __shfl_xor(tm, 16, 64));
    tm = fmaxf(tm, __shfl_xor(tm, 32, 64));
    float mn = fmaxf(m, tm);
    float psum = 0.f;
#pragma unroll
    for (int i = 0; i < 16; ++i) psum += ex2(sv[i] - mn);
    psum += __shfl_xor(psum, 16, 64);
    psum += __shfl_xor(psum, 32, 64);
    lsum = lsum * ex2(m - mn) + psum;
    m = mn;
    SFENCE(); BAR();
    cur ^= 1;
  }

  // stats handoff: per-q (indexed l&15) -> per-C-row (indexed (l>>4)*4+r)
  {
    float* stat = (float*)ps + w * 32;
    if (l < 16) { stat[l] = m; stat[16 + l] = 1.0f / lsum; }
  }
  __syncthreads();
  float mr[4], ivr[4];
  {
    const float* stat = (const float*)ps + w * 32;
#pragma unroll
    for (int r = 0; r < 4; ++r) {
      int q = (l >> 4) * 4 + r;
      mr[r] = stat[q];
      ivr[r] = stat[16 + q];
    }
  }

  // ---- pass 2: recompute S (unswapped), normalize, write p, accumulate PV ----
  f32x4 zf = {0.f, 0.f, 0.f, 0.f};
  f32x4 o[4];
#pragma unroll
  for (int nf = 0; nf < 4; ++nf) o[nf] = zf;

  stage_async64(ks[0], kptr(0), KS2, tid);
  stage_async64(vs[0], vptr(0), S_, tid);
  cur = 0;
  for (int it = 0; it < NT; ++it) {
    if (it + 1 < NT) {
      stage_async64(ks[cur ^ 1], kptr(it + 1), KS2, tid);
      stage_async64(vs[cur ^ 1], vptr(it + 1), S_, tid);
      if (it == 0) { WAITV(8); } else { WAITV(24); }  // queue: [loads_t(8)][stores(16)][loads_t+1(8)]
    } else {
      if (it == 0) { WAITV(0); } else { WAITV(16); }
    }
    BAR(); SFENCE();
    int domask = (it == nt - 1) || (it == NT - 1);
    int hf = it >= nt;
    int tbase = (it - (hf ? nt : 0)) * 64;
    f32x4 s[4];
    compute_S(ks[cur], qA0, qA1, l, domask, tbase, qrow0 + w * 16, s);
#pragma unroll
    for (int nf = 0; nf < 4; ++nf)
#pragma unroll
      for (int r = 0; r < 4; ++r) {
        int qr = qrow0 + w * 16 + (l >> 4) * 4 + r;
        float p = ex2(s[nf][r] - mr[r]) * ivr[r];
        int col = hf * S_ + tbase + nf * 16 + (l & 15);
        scores[((size_t)h * S_ + qr) * (2 * S_) + col] = p;
        int prow = w * 16 + (l >> 4) * 4 + r;
        int pcol = nf * 16 + (l & 15);
        ps[prow * 64 + ((pcol >> 3) ^ (prow & 7)) * 8 + (pcol & 7)] = f2bf(p);
      }
    // PV: each wave consumes only the ps rows it wrote
#pragma unroll
    for (int kk2 = 0; kk2 < 2; ++kk2) {
      bf16x8 pa = ld_frag64(ps, w * 16, kk2 * 4, l);
#pragma unroll
      for (int nf = 0; nf < 4; ++nf)
        o[nf] = mfma16(pa, ld_frag64(vs[cur], nf * 16, kk2 * 4, l), o[nf]);
    }
    SFENCE(); BAR();
    cur ^= 1;
  }
#pragma unroll
  for (int nf = 0; nf < 4; ++nf)
#pragma unroll
    for (int r = 0; r < 4; ++r) {
      int row = qrow0 + w * 16 + (l >> 4) * 4 + r;
      int col = h * HD_ + nf * 16 + (l & 15);
      ao[(size_t)row * D_ + col] = f2bf(o[nf][r]);
    }

  // ---- zero tail: cols [nt*64, 2048) of both halves for this block's 32 rows ----
  // Short-qt blocks finish attn fast and stream zeros while long blocks compute.
  int zc = 2048 - nt * 64;
  if (zc > 0) {
    int vph = zc >> 2;  // f32x4 per half per row (zc multiple of 64)
    f32x4 zero = {0.f, 0.f, 0.f, 0.f};
    float* base = scores + ((size_t)h * S_ + qrow0) * (2 * S_) + nt * 64;
    for (int row = 0; row < 32; ++row) {
      float* rp = base + (size_t)row * (2 * S_);
      for (int i = tid; i < vph; i += 128) *(f32x4*)(rp + i * 4) = zero;
      for (int i = tid; i < vph; i += 128) *(f32x4*)(rp + S_ + i * 4) = zero;
    }
  }
}

extern "C" void kernel_launch(void* const* d_in, const int* in_sizes, int n_in, void* d_out,
                              int out_size, void* d_ws, size_t ws_size, hipStream_t stream) {
  const float* hs = (const float*)d_in[0];
  const float* kn = (const float*)d_in[1];
  const float* Wq = (const float*)d_in[2];
  const float* Wkk = (const float*)d_in[3];
  const float* Wkm = (const float*)d_in[4];
  const float* Wvk = (const float*)d_in[5];
  const float* Wvm = (const float*)d_in[6];
  const float* Wo = (const float*)d_in[7];
  float* out = (float*)d_out;
  float* scores = out + (size_t)S_ * D_;

  const size_t M2 = (size_t)S_ * D_;  // 2M elems
  u16* ws = (u16*)d_ws;               // ~54 MB
  u16* hs_bf = ws;
  u16* kn_bf = hs_bf + M2;
  u16* WqT = kn_bf + M2;    // [1024][2048]
  u16* WkvkT = WqT + M2;    // [2048][1024]: rows 0-1023 Wkk^T, 1024-2047 Wvk^T
  u16* WkvmT = WkvkT + M2;  // same for mlp
  u16* WoT = WkvmT + M2;    // [1024][1024]
  u16* qb = WoT + M2 / 2;   // [2048][1024]
  u16* kvk = qb + M2;       // [2048][2048]: cols 0-1023 K_know, 1024-2047 V_know
  u16* kvm = kvk + 2 * M2;  // same for mlp
  u16* vkT = kvm + 2 * M2;  // [1024][2048] per-head [h][hd][s]
  u16* vmT = vkT + M2;
  u16* aob = vmT + M2;

  int n4 = (int)(M2 / 4);
  cast_all<<<(2 * n4 + 255) / 256, 256, 0, stream>>>(hs, kn, hs_bf, kn_bf, n4);
  castT_all<<<dim3(32, 224), 256, 0, stream>>>(Wq, Wkk, Wvk, Wkm, Wvm, Wo, WqT, WkvkT, WkvmT,
                                               WoT);
  proj_gemm<<<640, 256, 0, stream>>>(hs_bf, kn_bf, WqT, WkvkT, WkvmT, qb, kvk, kvm);
  transpose2<<<dim3(32, 64, 2), 256, 0, stream>>>(kvk + 1024, kvm + 1024, vkT, vmT);
  attn_kernel<<<1024, 128, 0, stream>>>(qb, kvk, kvm, vkT, vmT, scores, aob);
  out_gemm<<<dim3(8, 16), 256, 0, stream>>>(aob, WoT, out);
}

// Round 4
// 292.613 us; speedup vs baseline: 1.9823x; 1.0227x over previous
//
#include <hip/hip_runtime.h>

typedef unsigned short u16;
typedef float f32x4 __attribute__((ext_vector_type(4)));
typedef __bf16 bf16x8 __attribute__((ext_vector_type(8)));
typedef unsigned int u32x4 __attribute__((ext_vector_type(4)));
typedef u16 u16x4 __attribute__((ext_vector_type(4)));

#define S_ 2048
#define D_ 1024
#define H_ 16
#define HD_ 64

#define WAITV(N) asm volatile("s_waitcnt vmcnt(" #N ")" ::: "memory")
#define BAR() __builtin_amdgcn_s_barrier()
#define SFENCE() __builtin_amdgcn_sched_barrier(0)

__device__ __forceinline__ u16 f2bf(float f) {
  unsigned int u = __builtin_bit_cast(unsigned int, f);
  u += 0x7fffu + ((u >> 16) & 1u);
  return (u16)(u >> 16);
}

__device__ __forceinline__ f32x4 mfma16(bf16x8 a, bf16x8 b, f32x4 c) {
  return __builtin_amdgcn_mfma_f32_16x16x32_bf16(a, b, c, 0, 0, 0);
}

// 2^x via v_exp_f32 (s_nop covers the TRANS->VALU hazard window)
__device__ __forceinline__ float ex2(float x) {
  float r;
  asm("v_exp_f32 %0, %1\n\ts_nop 1" : "=v"(r) : "v"(x));
  return r;
}

// async global->LDS, 16B per lane. LDS dest must be linear in lane order.
__device__ __forceinline__ void gld_lds16(const u16* g, u16* l) {
  __builtin_amdgcn_global_load_lds((const __attribute__((address_space(1))) void*)g,
                                   (__attribute__((address_space(3))) void*)l, 16, 0, 0);
}

// ---------- cast both fp32 inputs -> bf16 (one launch) ----------
__global__ void cast_all(const float* __restrict__ a, const float* __restrict__ b,
                         u16* __restrict__ da, u16* __restrict__ db, int n4) {
  int i = blockIdx.x * 256 + threadIdx.x;
  const float* s;
  u16* d;
  int j;
  if (i < n4) { s = a; d = da; j = i; }
  else { j = i - n4; if (j >= n4) return; s = b; d = db; }
  f32x4 v = *(const f32x4*)(s + (size_t)j * 4);
  u16x4 o;
  o[0] = f2bf(v[0]); o[1] = f2bf(v[1]); o[2] = f2bf(v[2]); o[3] = f2bf(v[3]);
  *(u16x4*)(d + (size_t)j * 4) = o;
}

// ---------- cast + transpose all 6 weights (one launch) ----------
__global__ __launch_bounds__(256) void castT_all(
    const float* __restrict__ Wq, const float* __restrict__ Wkk, const float* __restrict__ Wvk,
    const float* __restrict__ Wkm, const float* __restrict__ Wvm, const float* __restrict__ Wo,
    u16* __restrict__ WqT, u16* __restrict__ WkvkT, u16* __restrict__ WkvmT,
    u16* __restrict__ WoT) {
  __shared__ float tile[32][33];
  int y = blockIdx.y;
  const float* W;
  u16* WT;
  int R, br;
  const size_t HM = (size_t)1024 * 1024;
  if (y < 64) { W = Wq; WT = WqT; R = 2048; br = y; }
  else {
    R = 1024; br = y & 31;
    switch ((y - 64) >> 5) {
      case 0: W = Wkk; WT = WkvkT; break;
      case 1: W = Wvk; WT = WkvkT + HM; break;
      case 2: W = Wkm; WT = WkvmT; break;
      case 3: W = Wvm; WT = WkvmT + HM; break;
      default: W = Wo; WT = WoT; break;
    }
  }
  int tx = threadIdx.x & 31, ty = threadIdx.x >> 5;
  int bc = blockIdx.x;
#pragma unroll
  for (int i = 0; i < 4; ++i)
    tile[ty + i * 8][tx] = W[(size_t)(br * 32 + ty + i * 8) * 1024 + bc * 32 + tx];
  __syncthreads();
#pragma unroll
  for (int i = 0; i < 4; ++i)
    WT[(size_t)(bc * 32 + ty + i * 8) * R + br * 32 + tx] = f2bf(tile[tx][ty + i * 8]);
}

// ---------- GEMM body: 128x128 tile, BK=32, 4 waves, dbuf + counted vmcnt ----------
// MODE 0: bf16 row-major C[m][n] (stride ldc)
// MODE 1: f32  row-major C[m][n] (stride ldc)
// MODE 2: bf16 transposed-to-vT: vT[n][m] (stride S_), 8B stores
template <int MODE>
__device__ __forceinline__ void gemm_body(const u16* A0, const u16* A1, int ksplit,
                                          const u16* BT, void* Cp, int K, int ldc, int bn,
                                          int bm) {
  __shared__ u16 As[2][128 * 32];
  __shared__ u16 Bs[2][128 * 32];
  const int tid = threadIdx.x, l = tid & 63, w = tid >> 6;
  const int wm = w >> 1, wn = w & 1;
  f32x4 zf = {0.f, 0.f, 0.f, 0.f};
  f32x4 acc[4][4];
#pragma unroll
  for (int mi = 0; mi < 4; ++mi)
#pragma unroll
    for (int ni = 0; ni < 4; ++ni) acc[mi][ni] = zf;

  auto STAGE = [&](int b, int t) {
    int k0 = t * 32;
#pragma unroll
    for (int i = 0; i < 2; ++i) {  // A: 128 rows x 4 chunks(16B), swizzled source
      int idx = tid + i * 256, r = idx >> 2, c = idx & 3;
      int sc = c ^ ((r >> 1) & 3);
      int k = k0 + sc * 8;
      const u16* src = (k < ksplit) ? (A0 + (size_t)(bm * 128 + r) * D_ + k)
                                    : (A1 + (size_t)(bm * 128 + r) * D_ + (k - ksplit));
      gld_lds16(src, As[b] + idx * 8);
    }
#pragma unroll
    for (int i = 0; i < 2; ++i) {  // B
      int idx = tid + i * 256, r = idx >> 2, c = idx & 3;
      int sc = c ^ ((r >> 1) & 3);
      gld_lds16(BT + (size_t)(bn * 128 + r) * K + k0 + sc * 8, Bs[b] + idx * 8);
    }
  };

  const int nt = K >> 5;
  STAGE(0, 0);
  int cur = 0;
  for (int t = 0; t < nt; ++t) {
    if (t + 1 < nt) { STAGE(cur ^ 1, t + 1); WAITV(4); } else { WAITV(0); }
    BAR(); SFENCE();
    bf16x8 af[4], bfr[4];
#pragma unroll
    for (int mi = 0; mi < 4; ++mi) {
      int row = wm * 64 + mi * 16 + (l & 15);
      int slot = (l >> 4) ^ ((row >> 1) & 3);
      af[mi] = __builtin_bit_cast(bf16x8, *(const u32x4*)(As[cur] + row * 32 + slot * 8));
    }
#pragma unroll
    for (int ni = 0; ni < 4; ++ni) {
      int row = wn * 64 + ni * 16 + (l & 15);
      int slot = (l >> 4) ^ ((row >> 1) & 3);
      bfr[ni] = __builtin_bit_cast(bf16x8, *(const u32x4*)(Bs[cur] + row * 32 + slot * 8));
    }
#pragma unroll
    for (int mi = 0; mi < 4; ++mi)
#pragma unroll
      for (int ni = 0; ni < 4; ++ni) acc[mi][ni] = mfma16(af[mi], bfr[ni], acc[mi][ni]);
    SFENCE(); BAR();
    cur ^= 1;
  }
#pragma unroll
  for (int mi = 0; mi < 4; ++mi)
#pragma unroll
    for (int ni = 0; ni < 4; ++ni) {
      if (MODE == 2) {  // vT[n][m0..m0+3], 8B contiguous
        u16x4 pk;
#pragma unroll
        for (int r = 0; r < 4; ++r) pk[r] = f2bf(acc[mi][ni][r]);
        int n = bn * 128 + wn * 64 + ni * 16 + (l & 15);
        int m0 = bm * 128 + wm * 64 + mi * 16 + (l >> 4) * 4;
        *(u16x4*)((u16*)Cp + (size_t)n * S_ + m0) = pk;
      } else {
#pragma unroll
        for (int r = 0; r < 4; ++r) {
          int row = bm * 128 + wm * 64 + mi * 16 + (l >> 4) * 4 + r;
          int col = bn * 128 + wn * 64 + ni * 16 + (l & 15);
          if (MODE == 1)
            ((float*)Cp)[(size_t)row * ldc + col] = acc[mi][ni][r];
          else
            ((u16*)Cp)[(size_t)row * ldc + col] = f2bf(acc[mi][ni][r]);
        }
      }
    }
}

// ---------- fused projections: Q | Kknow | VknowT | Kmlp | VmlpT in one launch ----------
__global__ __launch_bounds__(256) void proj_gemm(const u16* __restrict__ hs_bf,
                                                 const u16* __restrict__ kn_bf,
                                                 const u16* __restrict__ WqT,
                                                 const u16* __restrict__ WkvkT,
                                                 const u16* __restrict__ WkvmT,
                                                 u16* __restrict__ qb, u16* __restrict__ kk,
                                                 u16* __restrict__ km, u16* __restrict__ vkT,
                                                 u16* __restrict__ vmT) {
  int bid = blockIdx.x;                   // 640 blocks, 640%8==0
  int swz = (bid & 7) * 80 + (bid >> 3);  // XCD-contiguous chunks
  int bn = swz % 40, bm = swz / 40;
  const size_t HM = (size_t)1024 * 1024;
  const int BIG = 1 << 30;
  if (bn < 8) {
    gemm_body<0>(hs_bf, kn_bf, 1024, WqT, qb, 2048, 1024, bn, bm);
  } else if (bn < 16) {
    gemm_body<0>(kn_bf, kn_bf, BIG, WkvkT, kk, 1024, 1024, bn - 8, bm);
  } else if (bn < 24) {
    gemm_body<2>(kn_bf, kn_bf, BIG, WkvkT + HM, vkT, 1024, 0, bn - 16, bm);
  } else if (bn < 32) {
    gemm_body<0>(hs_bf, hs_bf, BIG, WkvmT, km, 1024, 1024, bn - 24, bm);
  } else {
    gemm_body<2>(hs_bf, hs_bf, BIG, WkvmT + HM, vmT, 1024, 0, bn - 32, bm);
  }
}

__global__ __launch_bounds__(256) void out_gemm(const u16* __restrict__ aob,
                                                const u16* __restrict__ WoT,
                                                float* __restrict__ out) {
  gemm_body<1>(aob, aob, 1 << 30, WoT, out, 1024, 1024, blockIdx.x, blockIdx.y);
}

// ---------- async 64x64 bf16 tile stage (XOR-swizzled via source), 4 issues/thread ----------
__device__ __forceinline__ void stage_async64(u16* dst, const u16* src, int stride, int tid) {
  int w = tid >> 6, l = tid & 63;
#pragma unroll
  for (int j = 0; j < 4; ++j) {
    int ci = (w * 4 + j) * 64 + l;  // 16B chunk index 0..511, linear per wave
    int r = ci >> 3, c = ci & 7;
    int sc = c ^ (r & 7);
    gld_lds16(src + (size_t)r * stride + sc * 8, dst + ci * 8);
  }
}

__device__ __forceinline__ bf16x8 ld_frag64(const u16* lds, int rowbase, int chunkbase, int l) {
  int row = rowbase + (l & 15);
  int chunk = chunkbase + (l >> 4);
  int slot = chunk ^ (row & 7);
  return __builtin_bit_cast(bf16x8, *(const u32x4*)(lds + row * 64 + slot * 8));
}

// ---------- fused attention + causal-complement zero tail ----------
// Both passes use SWAPPED QK^T (mfma(K,Q) -> C[key][q], q = lane&15):
// stats lane-local, scores stored 16B-wide, ps written 8B-wide, PV = mfma(V^T, P).
__global__ __launch_bounds__(128) void attn_kernel(const u16* __restrict__ qb,
                                                   const u16* __restrict__ kk,
                                                   const u16* __restrict__ km,
                                                   const u16* __restrict__ vkT,
                                                   const u16* __restrict__ vmT,
                                                   float* __restrict__ scores,
                                                   u16* __restrict__ ao) {
  const int fid = blockIdx.x;
  const int xcd = fid & 7, ixd = fid >> 3;
  const int g = xcd * 128 + ixd;  // 2 heads per XCD -> K/V L2-resident
  const int h = g >> 6;
  const int gq = g & 63;
  const int qt = (gq & 1) ? (gq >> 1) : (63 - (gq >> 1));  // pair large+small
  const int tid = threadIdx.x, w = tid >> 6, l = tid & 63;
  const int nt = (qt >> 1) + 1;  // 64-key tiles per half
  const int NT = 2 * nt;
  const int qrow0 = qt * 32;
  const int q16 = l & 15, c4 = l >> 4;
  const int qme = qrow0 + w * 16 + q16;  // this lane's q-row
  const float sc2 = 0.04508422f;         // log2(e)/32

  __shared__ u16 qs[32 * 64];
  __shared__ u16 ks[2][64 * 64];
  __shared__ u16 vs[2][64 * 64];
  __shared__ u16 ps[32 * 64];

  auto kptr = [&](int it) {
    int hf = it >= nt;
    int t = it - (hf ? nt : 0);
    const u16* kb = hf ? km : kk;
    return kb + (size_t)(t * 64) * 1024 + h * HD_;
  };
  auto vptr = [&](int it) {
    int hf = it >= nt;
    int t = it - (hf ? nt : 0);
    const u16* vb = hf ? vmT : vkT;
    return vb + (size_t)(h * HD_) * S_ + t * 64;
  };

  // stage Q (sync, swizzled write)
#pragma unroll
  for (int i = 0; i < 2; ++i) {
    int idx = tid + i * 128;  // 256 chunks
    int r = idx >> 3, c = idx & 7;
    u32x4 v = *(const u32x4*)(qb + (size_t)(qrow0 + r) * D_ + h * HD_ + c * 8);
    *(u32x4*)(qs + r * 64 + ((c ^ (r & 7)) * 8)) = v;
  }
  __syncthreads();  // full drain: vmcnt clean for counted waits below
  bf16x8 qA0 = ld_frag64(qs, w * 16, 0, l);
  bf16x8 qA1 = ld_frag64(qs, w * 16, 4, l);

  // ---- pass 1: stats (lane owns q=l&15; 2 shuffles per tile) ----
  float m = -1e30f, lsum = 0.f;
  stage_async64(ks[0], kptr(0), 1024, tid);
  int cur = 0;
  for (int it = 0; it < NT; ++it) {
    if (it + 1 < NT) { stage_async64(ks[cur ^ 1], kptr(it + 1), 1024, tid); WAITV(4); }
    else { WAITV(0); }
    BAR(); SFENCE();
    int domask = (it == nt - 1) || (it == NT - 1);
    int tbase = (it - (it >= nt ? nt : 0)) * 64;
    f32x4 zfv = {0.f, 0.f, 0.f, 0.f};
    float sv[16];
    float tm = -1e30f;
#pragma unroll
    for (int kf = 0; kf < 4; ++kf) {
      f32x4 z = zfv;
      z = mfma16(ld_frag64(ks[cur], kf * 16, 0, l), qA0, z);
      z = mfma16(ld_frag64(ks[cur], kf * 16, 4, l), qA1, z);
#pragma unroll
      for (int r = 0; r < 4; ++r) {
        float v = z[r];
        if (domask) {
          int key = tbase + kf * 16 + c4 * 4 + r;
          if (key > qme) v = -1e30f;
        }
        sv[kf * 4 + r] = v;
        tm = fmaxf(tm, v);
      }
    }
    tm = fmaxf(tm, __shfl_xor(tm, 16, 64));
    tm = fmaxf(tm, __shfl_xor(tm, 32, 64));
    float mn = fmaxf(m, tm);
    float mnc = mn * sc2;
    float psum = 0.f;
#pragma unroll
    for (int i = 0; i < 16; ++i) psum += ex2(__builtin_fmaf(sv[i], sc2, -mnc));
    psum += __shfl_xor(psum, 16, 64);
    psum += __shfl_xor(psum, 32, 64);
    lsum = lsum * ex2((m - mn) * sc2) + psum;
    m = mn;
    SFENCE(); BAR();
    cur ^= 1;
  }
  // p = 2^(sv*sc2 - moff), moff = m*sc2 + log2(lsum)
  const float moff = __builtin_fmaf(m, sc2, __log2f(lsum));

  // ---- pass 2: recompute S (swapped), write scores 16B-wide, PV via ps ----
  f32x4 zf = {0.f, 0.f, 0.f, 0.f};
  f32x4 o[4];
#pragma unroll
  for (int df = 0; df < 4; ++df) o[df] = zf;

  float* const srow0 = scores + ((size_t)h * S_ + qme) * (2 * S_) + c4 * 4;
  const int prow = w * 16 + q16;
  const int swz8 = (q16 & 7) << 1;

  stage_async64(ks[0], kptr(0), 1024, tid);
  stage_async64(vs[0], vptr(0), S_, tid);
  cur = 0;
  for (int it = 0; it < NT; ++it) {
    if (it + 1 < NT) {
      stage_async64(ks[cur ^ 1], kptr(it + 1), 1024, tid);
      stage_async64(vs[cur ^ 1], vptr(it + 1), S_, tid);
      if (it == 0) { WAITV(8); } else { WAITV(12); }
    } else {
      WAITV(4);  // NT>=2: last iter always has 4 prior stores pending
    }
    BAR(); SFENCE();
    int domask = (it == nt - 1) || (it == NT - 1);
    int hf = it >= nt;
    int tbase = (it - (hf ? nt : 0)) * 64;
    float pv[16];
#pragma unroll
    for (int kf = 0; kf < 4; ++kf) {
      f32x4 z = zf;
      z = mfma16(ld_frag64(ks[cur], kf * 16, 0, l), qA0, z);
      z = mfma16(ld_frag64(ks[cur], kf * 16, 4, l), qA1, z);
#pragma unroll
      for (int r = 0; r < 4; ++r) {
        float v = z[r];
        if (domask) {
          int key = tbase + kf * 16 + c4 * 4 + r;
          if (key > qme) v = -1e30f;
        }
        pv[kf * 4 + r] = ex2(__builtin_fmaf(v, sc2, -moff));
      }
    }
    // scores: 4 x 16B per lane
    float* srow = srow0 + hf * S_ + tbase;
#pragma unroll
    for (int kf = 0; kf < 4; ++kf) {
      f32x4 s4 = {pv[kf * 4], pv[kf * 4 + 1], pv[kf * 4 + 2], pv[kf * 4 + 3]};
      *(f32x4*)(srow + kf * 16) = s4;
    }
    // ps: 4 x 8B per lane, 8B-slot XOR swizzle (consistent with ld_frag64 reader)
#pragma unroll
    for (int kf = 0; kf < 4; ++kf) {
      u16x4 pk;
#pragma unroll
      for (int r = 0; r < 4; ++r) pk[r] = f2bf(pv[kf * 4 + r]);
      int slot8 = (kf * 4 + c4) ^ swz8;
      *(u16x4*)(ps + prow * 64 + slot8 * 4) = pk;
    }
    // PV: O^T[d][q] += V^T-frag x P-frag (wave reads only its own ps rows)
#pragma unroll
    for (int df = 0; df < 4; ++df)
#pragma unroll
      for (int kc = 0; kc < 2; ++kc)
        o[df] = mfma16(ld_frag64(vs[cur], df * 16, kc * 4, l),
                       ld_frag64(ps, w * 16, kc * 4, l), o[df]);
    SFENCE(); BAR();
    cur ^= 1;
  }
  // ao[q][h*64+d]: 4 x 8B per lane
#pragma unroll
  for (int df = 0; df < 4; ++df) {
    u16x4 pk;
#pragma unroll
    for (int r = 0; r < 4; ++r) pk[r] = f2bf(o[df][r]);
    *(u16x4*)(ao + (size_t)qme * D_ + h * HD_ + df * 16 + c4 * 4) = pk;
  }

  // ---- zero tail: cols [nt*64, 2048) of both halves for this block's 32 rows ----
  int zc = 2048 - nt * 64;
  if (zc > 0) {
    int vph = zc >> 2;
    f32x4 zero = {0.f, 0.f, 0.f, 0.f};
    float* base = scores + ((size_t)h * S_ + qrow0) * (2 * S_) + nt * 64;
    for (int row = 0; row < 32; ++row) {
      float* rp = base + (size_t)row * (2 * S_);
      for (int i = tid; i < vph; i += 128) *(f32x4*)(rp + i * 4) = zero;
      for (int i = tid; i < vph; i += 128) *(f32x4*)(rp + S_ + i * 4) = zero;
    }
  }
}

extern "C" void kernel_launch(void* const* d_in, const int* in_sizes, int n_in, void* d_out,
                              int out_size, void* d_ws, size_t ws_size, hipStream_t stream) {
  const float* hs = (const float*)d_in[0];
  const float* kn = (const float*)d_in[1];
  const float* Wq = (const float*)d_in[2];
  const float* Wkk = (const float*)d_in[3];
  const float* Wkm = (const float*)d_in[4];
  const float* Wvk = (const float*)d_in[5];
  const float* Wvm = (const float*)d_in[6];
  const float* Wo = (const float*)d_in[7];
  float* out = (float*)d_out;
  float* scores = out + (size_t)S_ * D_;

  const size_t M2 = (size_t)S_ * D_;  // 2M elems
  u16* ws = (u16*)d_ws;               // ~48 MB
  u16* hs_bf = ws;
  u16* kn_bf = hs_bf + M2;
  u16* WqT = kn_bf + M2;    // [1024][2048]
  u16* WkvkT = WqT + M2;    // [2048][1024]: rows 0-1023 Wkk^T, 1024-2047 Wvk^T
  u16* WkvmT = WkvkT + M2;  // same for mlp
  u16* WoT = WkvmT + M2;    // [1024][1024]
  u16* qb = WoT + M2 / 2;   // [2048][1024]
  u16* kk = qb + M2;        // [2048][1024] K_know
  u16* km = kk + M2;        // [2048][1024] K_mlp
  u16* vkT = km + M2;       // [1024][2048] per-head [h][hd][s]
  u16* vmT = vkT + M2;
  u16* aob = vmT + M2;

  int n4 = (int)(M2 / 4);
  cast_all<<<(2 * n4 + 255) / 256, 256, 0, stream>>>(hs, kn, hs_bf, kn_bf, n4);
  castT_all<<<dim3(32, 224), 256, 0, stream>>>(Wq, Wkk, Wvk, Wkm, Wvm, Wo, WqT, WkvkT, WkvmT,
                                               WoT);
  proj_gemm<<<640, 256, 0, stream>>>(hs_bf, kn_bf, WqT, WkvkT, WkvmT, qb, kk, km, vkT, vmT);
  attn_kernel<<<1024, 128, 0, stream>>>(qb, kk, km, vkT, vmT, scores, aob);
  out_gemm<<<dim3(8, 16), 256, 0, stream>>>(aob, WoT, out);
}

// Round 5
// 267.200 us; speedup vs baseline: 2.1708x; 1.0951x over previous
//
#include <hip/hip_runtime.h>

typedef unsigned short u16;
typedef float f32x4 __attribute__((ext_vector_type(4)));
typedef __bf16 bf16x8 __attribute__((ext_vector_type(8)));
typedef unsigned int u32x4 __attribute__((ext_vector_type(4)));
typedef u16 u16x4 __attribute__((ext_vector_type(4)));

#define S_ 2048
#define D_ 1024
#define H_ 16
#define HD_ 64

#define WAITV(N) asm volatile("s_waitcnt vmcnt(" #N ")" ::: "memory")
#define BAR() __builtin_amdgcn_s_barrier()
#define SFENCE() __builtin_amdgcn_sched_barrier(0)

__device__ __forceinline__ u16 f2bf(float f) {
  unsigned int u = __builtin_bit_cast(unsigned int, f);
  u += 0x7fffu + ((u >> 16) & 1u);
  return (u16)(u >> 16);
}

__device__ __forceinline__ f32x4 mfma16(bf16x8 a, bf16x8 b, f32x4 c) {
  return __builtin_amdgcn_mfma_f32_16x16x32_bf16(a, b, c, 0, 0, 0);
}

// 2^x via v_exp_f32 (s_nop covers the TRANS->VALU hazard window)
__device__ __forceinline__ float ex2(float x) {
  float r;
  asm("v_exp_f32 %0, %1\n\ts_nop 1" : "=v"(r) : "v"(x));
  return r;
}

// async global->LDS, 16B per lane. LDS dest must be linear in lane order.
__device__ __forceinline__ void gld_lds16(const u16* g, u16* l) {
  __builtin_amdgcn_global_load_lds((const __attribute__((address_space(1))) void*)g,
                                   (__attribute__((address_space(3))) void*)l, 16, 0, 0);
}

// ---------- prep: cast inputs + cast/transpose all weights (one launch) ----------
__global__ __launch_bounds__(256) void prep_kernel(
    const float* __restrict__ hs, const float* __restrict__ kn, const float* __restrict__ Wq,
    const float* __restrict__ Wkk, const float* __restrict__ Wvk, const float* __restrict__ Wkm,
    const float* __restrict__ Wvm, const float* __restrict__ Wo, u16* __restrict__ hs_bf,
    u16* __restrict__ kn_bf, u16* __restrict__ WqT, u16* __restrict__ WkvkT,
    u16* __restrict__ WkvmT, u16* __restrict__ WoT, int n4) {
  __shared__ float tile[32][33];
  int b = blockIdx.x;
  if (b < 4096) {  // cast path
    int i = b * 256 + threadIdx.x;
    const float* s;
    u16* d;
    int j;
    if (i < n4) { s = hs; d = hs_bf; j = i; }
    else { j = i - n4; if (j >= n4) return; s = kn; d = kn_bf; }
    f32x4 v = *(const f32x4*)(s + (size_t)j * 4);
    u16x4 o;
    o[0] = f2bf(v[0]); o[1] = f2bf(v[1]); o[2] = f2bf(v[2]); o[3] = f2bf(v[3]);
    *(u16x4*)(d + (size_t)j * 4) = o;
    return;
  }
  int idx = b - 4096;
  int bc = idx & 31, y = idx >> 5;  // y in [0,224)
  const float* W;
  u16* WT;
  int R, br;
  const size_t HM = (size_t)1024 * 1024;
  if (y < 64) { W = Wq; WT = WqT; R = 2048; br = y; }
  else {
    R = 1024; br = y & 31;
    switch ((y - 64) >> 5) {
      case 0: W = Wkk; WT = WkvkT; break;
      case 1: W = Wvk; WT = WkvkT + HM; break;
      case 2: W = Wkm; WT = WkvmT; break;
      case 3: W = Wvm; WT = WkvmT + HM; break;
      default: W = Wo; WT = WoT; break;
    }
  }
  int tx = threadIdx.x & 31, ty = threadIdx.x >> 5;
#pragma unroll
  for (int i = 0; i < 4; ++i)
    tile[ty + i * 8][tx] = W[(size_t)(br * 32 + ty + i * 8) * 1024 + bc * 32 + tx];
  __syncthreads();
#pragma unroll
  for (int i = 0; i < 4; ++i)
    WT[(size_t)(bc * 32 + ty + i * 8) * R + br * 32 + tx] = f2bf(tile[tx][ty + i * 8]);
}

// ---------- GEMM body: (MI*32)x(NI*32) tile, BK=32, 4 waves, dbuf + counted vmcnt ----------
// MODE 0: bf16 row-major C (stride ldc) | MODE 1: f32 row-major nt | MODE 2: bf16 vT[n][m]
template <int MODE, int MI, int NI>
__device__ __forceinline__ void gemm_body(const u16* A0, const u16* A1, int ksplit,
                                          const u16* BT, void* Cp, int K, int ldc, int bn,
                                          int bm) {
  constexpr int BM = MI * 32, BN = NI * 32;
  __shared__ u16 As[2][BM * 32];
  __shared__ u16 Bs[2][BN * 32];
  const int tid = threadIdx.x, l = tid & 63, w = tid >> 6;
  const int wm = w >> 1, wn = w & 1;
  f32x4 zf = {0.f, 0.f, 0.f, 0.f};
  f32x4 acc[MI][NI];
#pragma unroll
  for (int mi = 0; mi < MI; ++mi)
#pragma unroll
    for (int ni = 0; ni < NI; ++ni) acc[mi][ni] = zf;

  auto STAGE = [&](int b, int t) {
    int k0 = t * 32;
#pragma unroll
    for (int i = 0; i < MI / 2; ++i) {  // A: BM rows x 4 chunks(16B), swizzled source
      int idx = tid + i * 256, r = idx >> 2, c = idx & 3;
      int sc = c ^ ((r >> 1) & 3);
      int k = k0 + sc * 8;
      const u16* src = (k < ksplit) ? (A0 + (size_t)(bm * BM + r) * D_ + k)
                                    : (A1 + (size_t)(bm * BM + r) * D_ + (k - ksplit));
      gld_lds16(src, As[b] + idx * 8);
    }
#pragma unroll
    for (int i = 0; i < NI / 2; ++i) {  // B
      int idx = tid + i * 256, r = idx >> 2, c = idx & 3;
      int sc = c ^ ((r >> 1) & 3);
      gld_lds16(BT + (size_t)(bn * BN + r) * K + k0 + sc * 8, Bs[b] + idx * 8);
    }
  };

  const int nt = K >> 5;
  STAGE(0, 0);
  int cur = 0;
  for (int t = 0; t < nt; ++t) {
    if (t + 1 < nt) {
      STAGE(cur ^ 1, t + 1);
      if constexpr (MI + NI == 8) { WAITV(4); } else { WAITV(3); }
    } else {
      WAITV(0);
    }
    BAR(); SFENCE();
    bf16x8 af[MI], bfr[NI];
#pragma unroll
    for (int mi = 0; mi < MI; ++mi) {
      int row = wm * (MI * 16) + mi * 16 + (l & 15);
      int slot = (l >> 4) ^ ((row >> 1) & 3);
      af[mi] = __builtin_bit_cast(bf16x8, *(const u32x4*)(As[cur] + row * 32 + slot * 8));
    }
#pragma unroll
    for (int ni = 0; ni < NI; ++ni) {
      int row = wn * (NI * 16) + ni * 16 + (l & 15);
      int slot = (l >> 4) ^ ((row >> 1) & 3);
      bfr[ni] = __builtin_bit_cast(bf16x8, *(const u32x4*)(Bs[cur] + row * 32 + slot * 8));
    }
#pragma unroll
    for (int mi = 0; mi < MI; ++mi)
#pragma unroll
      for (int ni = 0; ni < NI; ++ni) acc[mi][ni] = mfma16(af[mi], bfr[ni], acc[mi][ni]);
    SFENCE(); BAR();
    cur ^= 1;
  }
#pragma unroll
  for (int mi = 0; mi < MI; ++mi)
#pragma unroll
    for (int ni = 0; ni < NI; ++ni) {
      if (MODE == 2) {  // vT[n][m0..m0+3], 8B contiguous
        u16x4 pk;
#pragma unroll
        for (int r = 0; r < 4; ++r) pk[r] = f2bf(acc[mi][ni][r]);
        int n = bn * BN + wn * (NI * 16) + ni * 16 + (l & 15);
        int m0 = bm * BM + wm * (MI * 16) + mi * 16 + (l >> 4) * 4;
        *(u16x4*)((u16*)Cp + (size_t)n * S_ + m0) = pk;
      } else {
#pragma unroll
        for (int r = 0; r < 4; ++r) {
          int row = bm * BM + wm * (MI * 16) + mi * 16 + (l >> 4) * 4 + r;
          int col = bn * BN + wn * (NI * 16) + ni * 16 + (l & 15);
          if (MODE == 1)
            __builtin_nontemporal_store(acc[mi][ni][r], (float*)Cp + (size_t)row * ldc + col);
          else
            ((u16*)Cp)[(size_t)row * ldc + col] = f2bf(acc[mi][ni][r]);
        }
      }
    }
}

// ---------- fused projections: Q | Kknow | VknowT | Kmlp | VmlpT in one launch ----------
__global__ __launch_bounds__(256) void proj_gemm(const u16* __restrict__ hs_bf,
                                                 const u16* __restrict__ kn_bf,
                                                 const u16* __restrict__ WqT,
                                                 const u16* __restrict__ WkvkT,
                                                 const u16* __restrict__ WkvmT,
                                                 u16* __restrict__ qb, u16* __restrict__ kk,
                                                 u16* __restrict__ km, u16* __restrict__ vkT,
                                                 u16* __restrict__ vmT) {
  int bid = blockIdx.x;                   // 640 blocks, 640%8==0
  int swz = (bid & 7) * 80 + (bid >> 3);  // XCD-contiguous chunks
  int bn = swz % 40, bm = swz / 40;
  const size_t HM = (size_t)1024 * 1024;
  const int BIG = 1 << 30;
  if (bn < 8) {
    gemm_body<0, 4, 4>(hs_bf, kn_bf, 1024, WqT, qb, 2048, 1024, bn, bm);
  } else if (bn < 16) {
    gemm_body<0, 4, 4>(kn_bf, kn_bf, BIG, WkvkT, kk, 1024, 1024, bn - 8, bm);
  } else if (bn < 24) {
    gemm_body<2, 4, 4>(kn_bf, kn_bf, BIG, WkvkT + HM, vkT, 1024, 0, bn - 16, bm);
  } else if (bn < 32) {
    gemm_body<0, 4, 4>(hs_bf, hs_bf, BIG, WkvmT, km, 1024, 1024, bn - 24, bm);
  } else {
    gemm_body<2, 4, 4>(hs_bf, hs_bf, BIG, WkvmT + HM, vmT, 1024, 0, bn - 32, bm);
  }
}

// ---------- output GEMM: 64x128 tiles, 256 blocks (1/CU), XCD-swizzled ----------
__global__ __launch_bounds__(256) void out_gemm(const u16* __restrict__ aob,
                                                const u16* __restrict__ WoT,
                                                float* __restrict__ out) {
  int bid = blockIdx.x;
  int xcd = bid & 7, i = bid >> 3;
  int bm = xcd * 4 + (i >> 3), bn = i & 7;
  gemm_body<1, 2, 4>(aob, aob, 1 << 30, WoT, out, 1024, 1024, bn, bm);
}

// ---------- async 64x64 bf16 tile stage (XOR-swizzled via source), 4 issues/thread ----------
__device__ __forceinline__ void stage_async64(u16* dst, const u16* src, int stride, int tid) {
  int w = tid >> 6, l = tid & 63;
#pragma unroll
  for (int j = 0; j < 4; ++j) {
    int ci = (w * 4 + j) * 64 + l;  // 16B chunk index 0..511, linear per wave
    int r = ci >> 3, c = ci & 7;
    int sc = c ^ (r & 7);
    gld_lds16(src + (size_t)r * stride + sc * 8, dst + ci * 8);
  }
}

__device__ __forceinline__ bf16x8 ld_frag64(const u16* lds, int rowbase, int chunkbase, int l) {
  int row = rowbase + (l & 15);
  int chunk = chunkbase + (l >> 4);
  int slot = chunk ^ (row & 7);
  return __builtin_bit_cast(bf16x8, *(const u32x4*)(lds + row * 64 + slot * 8));
}

// ---------- fused attention + causal-complement zero tail ----------
// Both passes use SWAPPED QK^T (mfma(K,Q) -> C[key][q], q = lane&15):
// stats lane-local, scores stored 16B-wide nt, ps written 8B-wide, PV = mfma(V^T, P).
__global__ __launch_bounds__(128) void attn_kernel(const u16* __restrict__ qb,
                                                   const u16* __restrict__ kk,
                                                   const u16* __restrict__ km,
                                                   const u16* __restrict__ vkT,
                                                   const u16* __restrict__ vmT,
                                                   float* __restrict__ scores,
                                                   u16* __restrict__ ao) {
  const int fid = blockIdx.x;
  const int xcd = fid & 7, ixd = fid >> 3;
  const int g = xcd * 128 + ixd;  // 2 heads per XCD -> K/V L2-resident
  const int h = g >> 6;
  const int gq = g & 63;
  const int qt = (gq & 1) ? (gq >> 1) : (63 - (gq >> 1));  // pair large+small
  const int tid = threadIdx.x, w = tid >> 6, l = tid & 63;
  const int nt = (qt >> 1) + 1;  // 64-key tiles per half
  const int NT = 2 * nt;
  const int qrow0 = qt * 32;
  const int q16 = l & 15, c4 = l >> 4;
  const int qme = qrow0 + w * 16 + q16;  // this lane's q-row
  const float sc2 = 0.04508422f;         // log2(e)/32

  __shared__ u16 qs[32 * 64];
  __shared__ u16 kv4[4][64 * 64];  // pass1: ring-4 K; pass2: [0..1]=K dbuf, [2..3]=V dbuf
  __shared__ u16 ps[32 * 64];

  auto kptr = [&](int it) {
    int hf = it >= nt;
    int t = it - (hf ? nt : 0);
    const u16* kb = hf ? km : kk;
    return kb + (size_t)(t * 64) * 1024 + h * HD_;
  };
  auto vptr = [&](int it) {
    int hf = it >= nt;
    int t = it - (hf ? nt : 0);
    const u16* vb = hf ? vmT : vkT;
    return vb + (size_t)(h * HD_) * S_ + t * 64;
  };

  // stage Q (sync, swizzled write)
#pragma unroll
  for (int i = 0; i < 2; ++i) {
    int idx = tid + i * 128;  // 256 chunks
    int r = idx >> 3, c = idx & 7;
    u32x4 v = *(const u32x4*)(qb + (size_t)(qrow0 + r) * D_ + h * HD_ + c * 8);
    *(u32x4*)(qs + r * 64 + ((c ^ (r & 7)) * 8)) = v;
  }
  __syncthreads();  // full drain: vmcnt clean for counted waits below
  bf16x8 qA0 = ld_frag64(qs, w * 16, 0, l);
  bf16x8 qA1 = ld_frag64(qs, w * 16, 4, l);

  // ---- pass 1: stats; ring-4 K buffers, depth-2 prefetch, ONE barrier/tile ----
  // (write target (it+2)&3 is never a buffer any wave can still be reading)
  float m = -1e30f, lsum = 0.f;
  stage_async64(kv4[0], kptr(0), 1024, tid);
  stage_async64(kv4[1], kptr(1), 1024, tid);  // NT >= 2 always
  for (int it = 0; it < NT; ++it) {
    if (it + 2 < NT) { stage_async64(kv4[(it + 2) & 3], kptr(it + 2), 1024, tid); WAITV(8); }
    else if (it + 1 < NT) { WAITV(4); }
    else { WAITV(0); }
    BAR(); SFENCE();
    const u16* ksb = kv4[it & 3];
    int domask = (it == nt - 1) || (it == NT - 1);
    int tbase = (it - (it >= nt ? nt : 0)) * 64;
    f32x4 zfv = {0.f, 0.f, 0.f, 0.f};
    float sv[16];
    float tm = -1e30f;
#pragma unroll
    for (int kf = 0; kf < 4; ++kf) {
      f32x4 z = zfv;
      z = mfma16(ld_frag64(ksb, kf * 16, 0, l), qA0, z);
      z = mfma16(ld_frag64(ksb, kf * 16, 4, l), qA1, z);
#pragma unroll
      for (int r = 0; r < 4; ++r) {
        float v = z[r];
        if (domask) {
          int key = tbase + kf * 16 + c4 * 4 + r;
          if (key > qme) v = -1e30f;
        }
        sv[kf * 4 + r] = v;
        tm = fmaxf(tm, v);
      }
    }
    tm = fmaxf(tm, __shfl_xor(tm, 16, 64));
    tm = fmaxf(tm, __shfl_xor(tm, 32, 64));
    float mn = fmaxf(m, tm);
    float mnc = mn * sc2;
    float psum = 0.f;
#pragma unroll
    for (int i = 0; i < 16; ++i) psum += ex2(__builtin_fmaf(sv[i], sc2, -mnc));
    psum += __shfl_xor(psum, 16, 64);
    psum += __shfl_xor(psum, 32, 64);
    lsum = lsum * ex2((m - mn) * sc2) + psum;
    m = mn;
    SFENCE();
  }
  BAR();  // all waves done with pass-1 buffers before pass-2 staging
  // p = 2^(sv*sc2 - moff), moff = m*sc2 + log2(lsum)
  const float moff = __builtin_fmaf(m, sc2, __log2f(lsum));

  // ---- pass 2: recompute S (swapped), write scores 16B nt, PV via ps ----
  f32x4 zf = {0.f, 0.f, 0.f, 0.f};
  f32x4 o[4];
#pragma unroll
  for (int df = 0; df < 4; ++df) o[df] = zf;

  float* const srow0 = scores + ((size_t)h * S_ + qme) * (2 * S_) + c4 * 4;
  const int prow = w * 16 + q16;
  const int swz8 = (q16 & 7) << 1;

  stage_async64(kv4[0], kptr(0), 1024, tid);
  stage_async64(kv4[2], vptr(0), S_, tid);
  int cur = 0;
  for (int it = 0; it < NT; ++it) {
    if (it + 1 < NT) {
      stage_async64(kv4[cur ^ 1], kptr(it + 1), 1024, tid);
      stage_async64(kv4[2 + (cur ^ 1)], vptr(it + 1), S_, tid);
      if (it == 0) { WAITV(8); } else { WAITV(12); }
    } else {
      WAITV(4);  // NT>=2: last iter always has 4 prior stores pending
    }
    BAR(); SFENCE();
    int domask = (it == nt - 1) || (it == NT - 1);
    int hf = it >= nt;
    int tbase = (it - (hf ? nt : 0)) * 64;
    float pv[16];
#pragma unroll
    for (int kf = 0; kf < 4; ++kf) {
      f32x4 z = zf;
      z = mfma16(ld_frag64(kv4[cur], kf * 16, 0, l), qA0, z);
      z = mfma16(ld_frag64(kv4[cur], kf * 16, 4, l), qA1, z);
#pragma unroll
      for (int r = 0; r < 4; ++r) {
        float v = z[r];
        if (domask) {
          int key = tbase + kf * 16 + c4 * 4 + r;
          if (key > qme) v = -1e30f;
        }
        pv[kf * 4 + r] = ex2(__builtin_fmaf(v, sc2, -moff));
      }
    }
    // scores: 4 x 16B nt per lane
    float* srow = srow0 + hf * S_ + tbase;
#pragma unroll
    for (int kf = 0; kf < 4; ++kf) {
      f32x4 s4 = {pv[kf * 4], pv[kf * 4 + 1], pv[kf * 4 + 2], pv[kf * 4 + 3]};
      __builtin_nontemporal_store(s4, (f32x4*)(srow + kf * 16));
    }
    // ps: 4 x 8B per lane, 8B-slot XOR swizzle (consistent with ld_frag64 reader)
#pragma unroll
    for (int kf = 0; kf < 4; ++kf) {
      u16x4 pk;
#pragma unroll
      for (int r = 0; r < 4; ++r) pk[r] = f2bf(pv[kf * 4 + r]);
      int slot8 = (kf * 4 + c4) ^ swz8;
      *(u16x4*)(ps + prow * 64 + slot8 * 4) = pk;
    }
    // PV: O^T[d][q] += V^T-frag x P-frag (wave reads only its own ps rows)
#pragma unroll
    for (int df = 0; df < 4; ++df)
#pragma unroll
      for (int kc = 0; kc < 2; ++kc)
        o[df] = mfma16(ld_frag64(kv4[2 + cur], df * 16, kc * 4, l),
                       ld_frag64(ps, w * 16, kc * 4, l), o[df]);
    SFENCE(); BAR();
    cur ^= 1;
  }
  // ao[q][h*64+d]: 4 x 8B nt per lane
#pragma unroll
  for (int df = 0; df < 4; ++df) {
    u16x4 pk;
#pragma unroll
    for (int r = 0; r < 4; ++r) pk[r] = f2bf(o[df][r]);
    __builtin_nontemporal_store(pk,
                                (u16x4*)(ao + (size_t)qme * D_ + h * HD_ + df * 16 + c4 * 4));
  }

  // ---- zero tail: cols [nt*64, 2048) of both halves for this block's 32 rows ----
  int zc = 2048 - nt * 64;
  if (zc > 0) {
    int vph = zc >> 2;
    f32x4 zero = {0.f, 0.f, 0.f, 0.f};
    float* base = scores + ((size_t)h * S_ + qrow0) * (2 * S_) + nt * 64;
    for (int row = 0; row < 32; ++row) {
      float* rp = base + (size_t)row * (2 * S_);
      for (int i = tid; i < vph; i += 128)
        __builtin_nontemporal_store(zero, (f32x4*)(rp + i * 4));
      for (int i = tid; i < vph; i += 128)
        __builtin_nontemporal_store(zero, (f32x4*)(rp + S_ + i * 4));
    }
  }
}

extern "C" void kernel_launch(void* const* d_in, const int* in_sizes, int n_in, void* d_out,
                              int out_size, void* d_ws, size_t ws_size, hipStream_t stream) {
  const float* hs = (const float*)d_in[0];
  const float* kn = (const float*)d_in[1];
  const float* Wq = (const float*)d_in[2];
  const float* Wkk = (const float*)d_in[3];
  const float* Wkm = (const float*)d_in[4];
  const float* Wvk = (const float*)d_in[5];
  const float* Wvm = (const float*)d_in[6];
  const float* Wo = (const float*)d_in[7];
  float* out = (float*)d_out;
  float* scores = out + (size_t)S_ * D_;

  const size_t M2 = (size_t)S_ * D_;  // 2M elems
  u16* ws = (u16*)d_ws;               // ~48 MB
  u16* hs_bf = ws;
  u16* kn_bf = hs_bf + M2;
  u16* WqT = kn_bf + M2;    // [1024][2048]
  u16* WkvkT = WqT + M2;    // [2048][1024]: rows 0-1023 Wkk^T, 1024-2047 Wvk^T
  u16* WkvmT = WkvkT + M2;  // same for mlp
  u16* WoT = WkvmT + M2;    // [1024][1024]
  u16* qb = WoT + M2 / 2;   // [2048][1024]
  u16* kk = qb + M2;        // [2048][1024] K_know
  u16* km = kk + M2;        // [2048][1024] K_mlp
  u16* vkT = km + M2;       // [1024][2048] per-head [h][hd][s]
  u16* vmT = vkT + M2;
  u16* aob = vmT + M2;

  int n4 = (int)(M2 / 4);
  prep_kernel<<<11264, 256, 0, stream>>>(hs, kn, Wq, Wkk, Wvk, Wkm, Wvm, Wo, hs_bf, kn_bf, WqT,
                                         WkvkT, WkvmT, WoT, n4);
  proj_gemm<<<640, 256, 0, stream>>>(hs_bf, kn_bf, WqT, WkvkT, WkvmT, qb, kk, km, vkT, vmT);
  attn_kernel<<<1024, 128, 0, stream>>>(qb, kk, km, vkT, vmT, scores, aob);
  out_gemm<<<256, 256, 0, stream>>>(aob, WoT, out);
}